// Round 9
// baseline (428.413 us; speedup 1.0000x reference)
//
#include <hip/hip_runtime.h>

#define NATOM 3840
#define NMOL 48
#define NPER 80
#define FD 128
#define KR 64
#define NBLOCK 5

constexpr float SR_CUT_C = 10.0f;
constexpr float KEHALF_C = 7.199822675975274f;
constexpr float LN2_C    = 0.6931471805599453f;

using bf16x8 = __attribute__((ext_vector_type(8))) short;
using f32x4  = __attribute__((ext_vector_type(4))) float;

__device__ __forceinline__ float sspf(float x) {
    return fmaxf(x, 0.0f) + __logf(1.0f + __expf(-fabsf(x))) - LN2_C;
}

// truncation split: v ~= hi + lo (both bf16), |err| <~ 2^-16 |v|
__device__ __forceinline__ void split2(float v, short& hi, short& lo) {
    unsigned u = __float_as_uint(v);
    hi = (short)(u >> 16);
    float l = v - __uint_as_float(u & 0xFFFF0000u);
    lo = (short)(__float_as_uint(l) >> 16);
}

// ---- mj fragment buffer: per molecule 24576 shorts/plane-pair ----
// [mol][plane(hi=0,lo=12288)][ch(4096)][f(32)][grp(8)][e]; value (jl, f):
// ch=jl>>5, grp=(jl>>3)&3, e=jl&7  (jl in [0,80); pad [80,96) zeroed once)
__device__ __forceinline__ void mj_store(short* mjTg, int gr, int f, float v) {
    int mol = gr / NPER;
    int jl  = gr - mol * NPER;
    short hi, lo; split2(v, hi, lo);
    size_t mo = (size_t)mol * 24576;
    int off = (jl >> 5) * 4096 + f * 32 + ((jl >> 3) & 3) * 8 + (jl & 7);
    mjTg[mo + off] = hi;
    mjTg[mo + 12288 + off] = lo;
}

// activation planes: [16 rows][128 f] shorts, 16B-slot XOR swizzle so A-frag
// ds_read_b128 (row = lane&15, slot = kt*4 + lane>>4) is bank-uniform.
__device__ __forceinline__ int plane_idx(int r, int f) {
    int s = f >> 3;
    int sp = (s & 8) | ((s ^ (r & 7)) & 7);
    return r * 128 + sp * 8 + (f & 7);
}

__device__ __forceinline__ void plane_store(short* Ahi, short* Alo, int r, int f, float v) {
    int idx = plane_idx(r, f);
    short hi, lo; split2(v, hi, lo);
    Ahi[idx] = hi; Alo[idx] = lo;
}

// wave w stages ITS OWN 16KB quarter of a prepped 64KB matrix into LDS.
__device__ __forceinline__ void stage_w_wave(short* dstBase, const short* srcBase, int w, int lane) {
#pragma unroll
    for (int it = 0; it < 16; ++it) {
        int boff = w * 16384 + it * 1024;
        __builtin_amdgcn_global_load_lds(
            (const __attribute__((address_space(1))) unsigned int*)((const char*)srcBase + boff + lane * 16),
            (__attribute__((address_space(3))) unsigned int*)((char*)dstBase + boff),
            16, 0, 0);
    }
}

// C[16 rows x 32 cols per wave] = planes(16x128) @ W(128x128)[cols fq0*16 .. fq0*16+31]
__device__ __forceinline__ void gemm_core(const short* Ahi, const short* Alo,
    const short* Wl, int lane, int fq0, f32x4 acc[2])
{
    const int r = lane & 15, h = lane >> 4;
    bf16x8 afh[4], afl[4];
#pragma unroll
    for (int kt = 0; kt < 4; ++kt) {
        int s = kt * 4 + h;
        int sp = (s & 8) | ((s ^ (r & 7)) & 7);
        afh[kt] = *(const bf16x8*)&Ahi[r * 128 + sp * 8];
        afl[kt] = *(const bf16x8*)&Alo[r * 128 + sp * 8];
    }
#pragma unroll
    for (int ft = 0; ft < 2; ++ft) {
        f32x4 a = {0.f, 0.f, 0.f, 0.f};
#pragma unroll
        for (int kt = 0; kt < 4; ++kt) {
            const short* bp = &Wl[((fq0 + ft) * 4 + kt) * 1024 + lane * 8];
            bf16x8 bh = *(const bf16x8*)bp;
            bf16x8 bl = *(const bf16x8*)(bp + 512);
            a = __builtin_amdgcn_mfma_f32_16x16x32_bf16(afh[kt], bl, a, 0, 0, 0);
            a = __builtin_amdgcn_mfma_f32_16x16x32_bf16(afl[kt], bh, a, 0, 0, 0);
            a = __builtin_amdgcn_mfma_f32_16x16x32_bf16(afh[kt], bh, a, 0, 0, 0);
        }
        acc[ft] = a;
    }
}

// ---------------- weight prep (unchanged) ----------------
__global__ __launch_bounds__(256) void k_prep(
    const float* __restrict__ Wi, const float* __restrict__ Wj,
    const float* __restrict__ rIW, const float* __restrict__ Wd,
    const float* __restrict__ rAW, const float* __restrict__ rOW,
    short* __restrict__ prepW)
{
    const int m = blockIdx.x, tid = threadIdx.x;
    const float* src;
    if (m == 65) src = Wi;
    else if (m == 66) src = Wj;
    else {
        int bb = m / 13, slot = m % 13;
        switch (slot) {
            case 0: case 1: case 2: case 3:
                src = rIW + (size_t)((bb * 2 + (slot >> 1)) * 2 + (slot & 1)) * 16384; break;
            case 4: src = Wd + (size_t)bb * 16384; break;
            case 5: case 6: case 7: case 8: {
                int ss = slot - 5;
                src = rAW + (size_t)((bb * 2 + (ss >> 1)) * 2 + (ss & 1)) * 16384; break;
            }
            case 9:  src = Wi + (size_t)((bb + 1 < 5) ? (bb + 1) : 0) * 16384; break;
            case 10: src = Wj + (size_t)((bb + 1 < 5) ? (bb + 1) : 0) * 16384; break;
            default: src = rOW + (size_t)(bb * 2 + (slot - 11)) * 16384; break;
        }
    }
    short* dst = prepW + (size_t)m * 32768;
#pragma unroll
    for (int i = 0; i < 8; ++i) {
        int tr = tid + i * 256;
        int ft = tr >> 8, kt = (tr >> 6) & 3, l = tr & 63;
        int f = ft * 16 + (l & 15);
        int k0 = kt * 32 + (l >> 4) * 8;
        bf16x8 hi8, lo8;
#pragma unroll
        for (int e = 0; e < 8; ++e) {
            float v = src[(size_t)(k0 + e) * FD + f];
            short hh, ll; split2(v, hh, ll);
            hi8[e] = hh; lo8[e] = ll;
        }
        size_t o = (size_t)(ft * 4 + kt) * 1024 + (size_t)l * 8;
        *(bf16x8*)&dst[o] = hi8;
        *(bf16x8*)&dst[o + 512] = lo8;
    }
}

// ---------------- k_first (unchanged) ----------------
__global__ __launch_bounds__(256) void k_first(
    const int* __restrict__ Za, const float* __restrict__ emb,
    const short* __restrict__ Wprep,
    const float* __restrict__ bi, const float* __restrict__ bj,
    float* __restrict__ X, float* __restrict__ MI, short* __restrict__ mjTg,
    float* __restrict__ Ea, float* __restrict__ Qa)
{
    __shared__ short Ahi[2048], Alo[2048];
    __shared__ short Wl[2][32768];
    const int tid = threadIdx.x, lane = tid & 63, w = tid >> 6;
    const int row0 = blockIdx.x * 16;
    const int fq0 = w * 2;
    const int col0 = w * 32 + (lane & 15), col1 = col0 + 16;
    const int hh = lane >> 4;

    stage_w_wave(Wl[0], Wprep + (size_t)65 * 32768, w, lane);   // Wi(0)

    for (int idx = tid; idx < 2048; idx += 256) {
        int rr = idx >> 7, f = idx & 127;
        float v = emb[(size_t)Za[row0 + rr] * FD + f];
        X[(size_t)(row0 + rr) * FD + f] = v;
        plane_store(Ahi, Alo, rr, f, sspf(v));
    }
    if (tid < 16) { Ea[row0 + tid] = 0.f; Qa[row0 + tid] = 0.f; }
    if ((row0 % NPER) == 0) {
        short* mb = mjTg + (size_t)(row0 / NPER) * 24576;
        for (int idx = tid; idx < 2048; idx += 256) {
            int f = idx >> 4, t = idx & 15;
            mb[8192 + f * 32 + 16 + t] = 0;
            mb[12288 + 8192 + f * 32 + 16 + t] = 0;
        }
    }
    __syncthreads();

    stage_w_wave(Wl[1], Wprep + (size_t)66 * 32768, w, lane);   // Wj(0)

    f32x4 acc[2];
    gemm_core(Ahi, Alo, Wl[0], lane, fq0, acc);
    {
        float b0 = bi[col0], b1 = bi[col1];
#pragma unroll
        for (int reg = 0; reg < 4; ++reg) {
            int rw = hh * 4 + reg;
            MI[(size_t)(row0 + rw) * FD + col0] = sspf(acc[0][reg] + b0);
            MI[(size_t)(row0 + rw) * FD + col1] = sspf(acc[1][reg] + b1);
        }
    }
    asm volatile("s_waitcnt vmcnt(0)" ::: "memory");
    gemm_core(Ahi, Alo, Wl[1], lane, fq0, acc);
    {
        float b0 = bj[col0], b1 = bj[col1];
#pragma unroll
        for (int reg = 0; reg < 4; ++reg) {
            int gr = row0 + hh * 4 + reg;
            mj_store(mjTg, gr, col0, sspf(acc[0][reg] + b0));
            mj_store(mjTg, gr, col1, sspf(acc[1][reg] + b1));
        }
    }
}

// ---------------- k_tail (unchanged) ----------------
__global__ __launch_bounds__(256) void k_tail(
    const float* __restrict__ M, float* __restrict__ X,
    const short* __restrict__ Wprep, int b,
    const float* __restrict__ rIb, const float* __restrict__ bd,
    const float* __restrict__ u, const float* __restrict__ rAb,
    const float* __restrict__ bi, const float* __restrict__ bj,
    const float* __restrict__ rOb, const float* __restrict__ Wout,
    const float* __restrict__ bout,
    float* __restrict__ MI, short* __restrict__ mjTg,
    float* __restrict__ Ea, float* __restrict__ Qa)
{
    __shared__ short Ahi[2048], Alo[2048];
    __shared__ short Wl[2][32768];
    __shared__ float eq[16][5][2];

    const int tid = threadIdx.x, lane = tid & 63, w = tid >> 6;
    const int row0 = blockIdx.x * 16;
    const int NG = (b < 4) ? 13 : 11;
    const int fq0 = w * 2;
    const int col0 = w * 32 + (lane & 15), col1 = col0 + 16;
    const int hh = lane >> 4;

    auto lgOf = [&](int gg) { return (b < 4 || gg < 9) ? gg : gg + 2; };

    stage_w_wave(Wl[0], Wprep + (size_t)(b * 13 + lgOf(0)) * 32768, w, lane);

    float vreg[2][4], xreg[2][4];
#pragma unroll
    for (int reg = 0; reg < 4; ++reg) {
        int rw = hh * 4 + reg;
        vreg[0][reg] = M[(size_t)(row0 + rw) * FD + col0];
        vreg[1][reg] = M[(size_t)(row0 + rw) * FD + col1];
        xreg[0][reg] = X[(size_t)(row0 + rw) * FD + col0];
        xreg[1][reg] = X[(size_t)(row0 + rw) * FD + col1];
    }
    for (int idx = tid; idx < 2048; idx += 256) {
        int rr = idx >> 7, f = idx & 127;
        plane_store(Ahi, Alo, rr, f, sspf(M[(size_t)(row0 + rr) * FD + f]));
    }
    __syncthreads();

    f32x4 acc[2];
    for (int g = 0; g < NG; ++g) {
        const int cur = g & 1;
        if (g > 0) {
            asm volatile("s_waitcnt lgkmcnt(0)\n\ts_barrier" ::: "memory");
            asm volatile("s_waitcnt vmcnt(0)" ::: "memory");
        }
        if (g + 1 < NG)
            stage_w_wave(Wl[cur ^ 1], Wprep + (size_t)(b * 13 + lgOf(g + 1)) * 32768, w, lane);

        gemm_core(Ahi, Alo, Wl[cur], lane, fq0, acc);

        int lg = lgOf(g);
        const float* bptr;
        switch (lg) {
            case 0:  bptr = rIb + ((size_t)(b * 2 + 0) * 2 + 0) * FD; break;
            case 1:  bptr = rIb + ((size_t)(b * 2 + 0) * 2 + 1) * FD; break;
            case 2:  bptr = rIb + ((size_t)(b * 2 + 1) * 2 + 0) * FD; break;
            case 3:  bptr = rIb + ((size_t)(b * 2 + 1) * 2 + 1) * FD; break;
            case 4:  bptr = bd + (size_t)b * FD; break;
            case 5:  bptr = rAb + ((size_t)(b * 2 + 0) * 2 + 0) * FD; break;
            case 6:  bptr = rAb + ((size_t)(b * 2 + 0) * 2 + 1) * FD; break;
            case 7:  bptr = rAb + ((size_t)(b * 2 + 1) * 2 + 0) * FD; break;
            case 8:  bptr = rAb + ((size_t)(b * 2 + 1) * 2 + 1) * FD; break;
            case 9:  bptr = bi + (size_t)(b + 1) * FD; break;
            case 10: bptr = bj + (size_t)(b + 1) * FD; break;
            case 11: bptr = rOb + (size_t)(b * 2 + 0) * FD; break;
            default: bptr = rOb + (size_t)(b * 2 + 1) * FD; break;
        }
        float bv0 = bptr[col0], bv1 = bptr[col1];
        float uv0 = 0.f, uv1 = 0.f;
        if (lg == 4) { uv0 = u[(size_t)b * FD + col0]; uv1 = u[(size_t)b * FD + col1]; }

        asm volatile("s_waitcnt lgkmcnt(0)\n\ts_barrier" ::: "memory");

        const bool isT = (lg == 0) | (lg == 2) | (lg == 5) | (lg == 7) | (lg == 11);
        const bool isV = (lg == 1) | (lg == 3) | (lg == 6) | (lg == 8) | (lg == 12);
        if (isT) {
#pragma unroll
            for (int reg = 0; reg < 4; ++reg) {
                int rw = hh * 4 + reg;
                plane_store(Ahi, Alo, rw, col0, sspf(acc[0][reg] + bv0));
                plane_store(Ahi, Alo, rw, col1, sspf(acc[1][reg] + bv1));
            }
        } else if (isV) {
#pragma unroll
            for (int reg = 0; reg < 4; ++reg) {
                int rw = hh * 4 + reg;
                float nv0 = acc[0][reg] + bv0 + vreg[0][reg];
                float nv1 = acc[1][reg] + bv1 + vreg[1][reg];
                vreg[0][reg] = nv0; vreg[1][reg] = nv1;
                if (lg != 12) {
                    plane_store(Ahi, Alo, rw, col0, sspf(nv0));
                    plane_store(Ahi, Alo, rw, col1, sspf(nv1));
                }
                if (lg == 8) {
                    X[(size_t)(row0 + rw) * FD + col0] = nv0;
                    X[(size_t)(row0 + rw) * FD + col1] = nv1;
                }
            }
        } else if (lg == 4) {
#pragma unroll
            for (int reg = 0; reg < 4; ++reg) {
                int rw = hh * 4 + reg;
                float nv0 = acc[0][reg] + bv0 + uv0 * xreg[0][reg];
                float nv1 = acc[1][reg] + bv1 + uv1 * xreg[1][reg];
                vreg[0][reg] = nv0; vreg[1][reg] = nv1;
                plane_store(Ahi, Alo, rw, col0, sspf(nv0));
                plane_store(Ahi, Alo, rw, col1, sspf(nv1));
            }
        } else if (lg == 9) {
#pragma unroll
            for (int reg = 0; reg < 4; ++reg) {
                int rw = hh * 4 + reg;
                MI[(size_t)(row0 + rw) * FD + col0] = sspf(acc[0][reg] + bv0);
                MI[(size_t)(row0 + rw) * FD + col1] = sspf(acc[1][reg] + bv1);
            }
        } else {
#pragma unroll
            for (int reg = 0; reg < 4; ++reg) {
                int gr = row0 + hh * 4 + reg;
                mj_store(mjTg, gr, col0, sspf(acc[0][reg] + bv0));
                mj_store(mjTg, gr, col1, sspf(acc[1][reg] + bv1));
            }
        }
    }
    float pe[4], pq[4];
#pragma unroll
    for (int reg = 0; reg < 4; ++reg) {
        float s0 = sspf(vreg[0][reg]), s1 = sspf(vreg[1][reg]);
        pe[reg] = s0 * Wout[col0 * 2 + 0] + s1 * Wout[col1 * 2 + 0];
        pq[reg] = s0 * Wout[col0 * 2 + 1] + s1 * Wout[col1 * 2 + 1];
#pragma unroll
        for (int mk = 1; mk < 16; mk <<= 1) {
            pe[reg] += __shfl_xor(pe[reg], mk);
            pq[reg] += __shfl_xor(pq[reg], mk);
        }
        if ((lane & 15) == 0) {
            eq[hh * 4 + reg][w][0] = pe[reg];
            eq[hh * 4 + reg][w][1] = pq[reg];
        }
    }
    __syncthreads();
    if (tid < 16) {
        float e = eq[tid][0][0] + eq[tid][1][0] + eq[tid][2][0] + eq[tid][3][0];
        float q = eq[tid][0][1] + eq[tid][1][1] + eq[tid][2][1] + eq[tid][3][1];
        Ea[row0 + tid] += e + bout[0];
        Qa[row0 + tid] += q + bout[1];
    }
}

// ---------------- k_msg: f-split x2 -> acc[4][4], 2 waves/atom, 3 waves/SIMD ----------------
__global__ __launch_bounds__(256, 3) void k_msg(
    const float* __restrict__ Ra, const float* __restrict__ MI,
    const short* __restrict__ mjTg, const float* __restrict__ centers,
    const float* __restrict__ widths, const float* __restrict__ Wrbf,
    float* __restrict__ MOUT)
{
    __shared__ float Wt[8192];          // 32 KB
    __shared__ float px[NPER], py[NPER], pz[NPER];

    const int tid  = threadIdx.x;
    const int lane = tid & 63;
    const int wave = tid >> 6;
    const int mol  = blockIdx.x / (NPER / 2);
    const int ig   = blockIdx.x % (NPER / 2);
    const int base = mol * NPER;
    const int i    = ig * 2 + (wave >> 1);   // 2 atoms per block
    const int fh   = wave & 1;               // f-half of this wave

    const int col = lane & 15;
    const int grp = lane >> 4;

    for (int idx = tid; idx < KR * FD; idx += 256) {
        int k = idx >> 7, f = idx & 127;
        Wt[(k >> 2) * 512 + f * 4 + (k & 3)] = Wrbf[idx];
    }
    if (tid < NPER) {
        px[tid] = Ra[(size_t)(base + tid) * 3 + 0];
        py[tid] = Ra[(size_t)(base + tid) * 3 + 1];
        pz[tid] = Ra[(size_t)(base + tid) * 3 + 2];
    }

    float cent[4], wid[4];
#pragma unroll
    for (int kt = 0; kt < 4; ++kt) {
        cent[kt] = centers[kt * 16 + col];
        wid[kt]  = widths[kt * 16 + col];
    }

    f32x4 acc[4][4];
#pragma unroll
    for (int kt = 0; kt < 4; ++kt)
#pragma unroll
        for (int ft = 0; ft < 4; ++ft)
            acc[kt][ft] = (f32x4){0.f, 0.f, 0.f, 0.f};

    __syncthreads();   // Wt + positions ready (only barrier in the kernel)

    const float xi = px[i], yi = py[i], zi = pz[i];
    const short* mb = mjTg + (size_t)mol * 24576;

    for (int ch = 0; ch < 3; ++ch) {
        // A fragments (rbf) in-register
        bf16x8 Ahi[4], Alo[4];
#pragma unroll
        for (int e = 0; e < 8; ++e) {
            int jg = ch * 32 + grp * 8 + e;
            float ed = 0.f, cut = 0.f;
            if (jg < NPER) {
                float dx = px[jg] - xi, dy = py[jg] - yi, dz = pz[jg] - zi;
                float d = sqrtf(dx * dx + dy * dy + dz * dz);
                ed = __expf(-d);
                if (jg != i && d < SR_CUT_C) {
                    float xr = d * (1.0f / SR_CUT_C);
                    float xr2 = xr * xr, xr3 = xr2 * xr;
                    cut = 1.0f - xr3 * (6.0f * xr2 - 15.0f * xr + 10.0f);
                }
            }
#pragma unroll
            for (int kt = 0; kt < 4; ++kt) {
                float t = ed - cent[kt];
                float val = cut * __expf(-wid[kt] * t * t);
                unsigned uv = __float_as_uint(val);
                Ahi[kt][e] = (short)(uv >> 16);
                float lv = val - __uint_as_float(uv & 0xFFFF0000u);
                Alo[kt][e] = (short)(__float_as_uint(lv) >> 16);
            }
        }

        const short* cb = mb + ch * 4096 + col * 32 + grp * 8;
#pragma unroll
        for (int ftl = 0; ftl < 4; ++ftl) {
            const int ftg = fh * 4 + ftl;
            bf16x8 bhi = *(const bf16x8*)(cb + ftg * 512);
            bf16x8 blo = *(const bf16x8*)(cb + 12288 + ftg * 512);
            __builtin_amdgcn_s_setprio(1);
#pragma unroll
            for (int kt = 0; kt < 4; ++kt) {
                acc[kt][ftl] = __builtin_amdgcn_mfma_f32_16x16x32_bf16(Ahi[kt], bhi, acc[kt][ftl], 0, 0, 0);
                acc[kt][ftl] = __builtin_amdgcn_mfma_f32_16x16x32_bf16(Alo[kt], bhi, acc[kt][ftl], 0, 0, 0);
                acc[kt][ftl] = __builtin_amdgcn_mfma_f32_16x16x32_bf16(Ahi[kt], blo, acc[kt][ftl], 0, 0, 0);
            }
            __builtin_amdgcn_s_setprio(0);
        }
    }

    // epilogue: part[ftl] = sum_k Wrbf[k,f] * T[k,f], f = (fh*4+ftl)*16+col
    float part[4];
#pragma unroll
    for (int ftl = 0; ftl < 4; ++ftl) part[ftl] = 0.f;
#pragma unroll
    for (int kt = 0; kt < 4; ++kt) {
        const float* wrow = &Wt[(kt * 4 + grp) * 512 + col * 4];
#pragma unroll
        for (int ftl = 0; ftl < 4; ++ftl) {
            float4 w4 = *(const float4*)(wrow + (fh * 4 + ftl) * 64);
            part[ftl] += acc[kt][ftl].x * w4.x + acc[kt][ftl].y * w4.y
                       + acc[kt][ftl].z * w4.z + acc[kt][ftl].w * w4.w;
        }
    }
#pragma unroll
    for (int ftl = 0; ftl < 4; ++ftl) {
        part[ftl] += __shfl_xor(part[ftl], 16);
        part[ftl] += __shfl_xor(part[ftl], 32);
    }
    // lane writes f = fh*64 + lane (ftl == grp selector, as f = ftl*16+col = lane)
    float p = (grp == 0) ? part[0] : (grp == 1) ? part[1] : (grp == 2) ? part[2] : part[3];
    const size_t go = (size_t)(base + i) * FD + fh * 64 + lane;
    MOUT[go] = MI[go] + p;
}

// ---------------- finale (unchanged) ----------------
__global__ __launch_bounds__(256) void k_final(
    const int* __restrict__ Za, const float* __restrict__ Ra,
    const float* __restrict__ Escale, const float* __restrict__ Eshift,
    const float* __restrict__ Qscale, const float* __restrict__ Qshift,
    const float* __restrict__ Ea, const float* __restrict__ Qa,
    float* __restrict__ out)
{
    __shared__ float qs[NPER], es[NPER], px[NPER], py[NPER], pz[NPER];
    __shared__ float red[256];
    const int mol = blockIdx.x, t = threadIdx.x;
    float q = 0.f;
    if (t < NPER) {
        int a = mol * NPER + t;
        int z = Za[a];
        es[t] = Escale[z] * Ea[a] + Eshift[z];
        q = Qscale[z] * Qa[a] + Qshift[z];
        px[t] = Ra[(size_t)a * 3 + 0];
        py[t] = Ra[(size_t)a * 3 + 1];
        pz[t] = Ra[(size_t)a * 3 + 2];
    }
    red[t] = q;
    __syncthreads();
    for (int s = 128; s > 0; s >>= 1) {
        if (t < s) red[t] += red[t + s];
        __syncthreads();
    }
    float qavg = red[0] / (float)NPER;
    __syncthreads();
    if (t < NPER) qs[t] = q - qavg;
    red[t] = 0.f;
    __syncthreads();

    float local = 0.f;
    const float c = SR_CUT_C * 0.5f;
    for (int p = t; p < NPER * NPER; p += 256) {
        int i = p / NPER, j = p % NPER;
        if (i == j) continue;
        float dx = px[i] - px[j], dy = py[i] - py[j], dz = pz[i] - pz[j];
        float d2 = dx * dx + dy * dy + dz * dz;
        float d = sqrtf(d2);
        float dS = sqrtf(d2 + 1.0f);
        float sw;
        if (d < c) {
            float xs = d / c;
            float xs2 = xs * xs, xs3 = xs2 * xs;
            sw = xs3 * (6.0f * xs2 - 15.0f * xs + 10.0f);
        } else {
            sw = 1.0f;
        }
        local += KEHALF_C * qs[i] * qs[j] * ((1.0f - sw) / dS + sw / d);
    }
    for (int a = t; a < NPER; a += 256) local += es[a];
    red[t] = local;
    __syncthreads();
    for (int s = 128; s > 0; s >>= 1) {
        if (t < s) red[t] += red[t + s];
        __syncthreads();
    }
    if (t == 0) out[mol] = red[0];
}

extern "C" void kernel_launch(void* const* d_in, const int* in_sizes, int n_in,
                              void* d_out, int out_size, void* d_ws, size_t ws_size,
                              hipStream_t stream)
{
    (void)in_sizes; (void)n_in; (void)out_size; (void)ws_size;

    const int*   Za     = (const int*)d_in[0];
    const float* Ra     = (const float*)d_in[1];
    const float* emb    = (const float*)d_in[5];
    const float* rbfc   = (const float*)d_in[6];
    const float* rbfw   = (const float*)d_in[7];
    const float* Wrbf   = (const float*)d_in[8];
    const float* Wi     = (const float*)d_in[9];
    const float* bi     = (const float*)d_in[10];
    const float* Wj     = (const float*)d_in[11];
    const float* bj     = (const float*)d_in[12];
    const float* rIW    = (const float*)d_in[13];
    const float* rIb    = (const float*)d_in[14];
    const float* Wd     = (const float*)d_in[15];
    const float* bd     = (const float*)d_in[16];
    const float* u      = (const float*)d_in[17];
    const float* rAW    = (const float*)d_in[18];
    const float* rAb    = (const float*)d_in[19];
    const float* rOW    = (const float*)d_in[20];
    const float* rOb    = (const float*)d_in[21];
    const float* Wout   = (const float*)d_in[22];
    const float* bout   = (const float*)d_in[23];
    const float* Escale = (const float*)d_in[24];
    const float* Eshift = (const float*)d_in[25];
    const float* Qscale = (const float*)d_in[26];
    const float* Qshift = (const float*)d_in[27];
    float* outp = (float*)d_out;

    float* ws = (float*)d_ws;
    const size_t NF = (size_t)NATOM * FD;
    float* x  = ws;
    float* mi = ws + NF;
    float* m  = ws + 2 * NF;
    float* Ea = ws + 3 * NF;
    float* Qa = Ea + NATOM;
    short* prepW = (short*)(ws + 3 * NF + 2 * NATOM);
    short* mjTg  = prepW + (size_t)67 * 32768;

    k_prep<<<67, 256, 0, stream>>>(Wi, Wj, rIW, Wd, rAW, rOW, prepW);
    k_first<<<NATOM / 16, 256, 0, stream>>>(Za, emb, prepW, bi, bj, x, mi, mjTg, Ea, Qa);

    for (int b = 0; b < NBLOCK; ++b) {
        k_msg<<<NMOL * (NPER / 2), 256, 0, stream>>>(
            Ra, mi, mjTg, rbfc, rbfw, Wrbf + (size_t)b * KR * FD, m);
        k_tail<<<NATOM / 16, 256, 0, stream>>>(
            m, x, prepW, b, rIb, bd, u, rAb, bi, bj, rOb,
            Wout + (size_t)b * FD * 2, bout + b * 2, mi, mjTg, Ea, Qa);
    }

    k_final<<<NMOL, 256, 0, stream>>>(Za, Ra, Escale, Eshift, Qscale, Qshift, Ea, Qa, outp);
}

// Round 10
// 348.548 us; speedup vs baseline: 1.2291x; 1.2291x over previous
//
#include <hip/hip_runtime.h>

#define NATOM 3840
#define NMOL 48
#define NPER 80
#define FD 128
#define KR 64
#define NBLOCK 5

constexpr float SR_CUT_C = 10.0f;
constexpr float KEHALF_C = 7.199822675975274f;
constexpr float LN2_C    = 0.6931471805599453f;

using bf16x8 = __attribute__((ext_vector_type(8))) short;
using f32x4  = __attribute__((ext_vector_type(4))) float;

__device__ __forceinline__ float sspf(float x) {
    return fmaxf(x, 0.0f) + __logf(1.0f + __expf(-fabsf(x))) - LN2_C;
}

// truncation split: v ~= hi + lo (both bf16), |err| <~ 2^-16 |v|
__device__ __forceinline__ void split2(float v, short& hi, short& lo) {
    unsigned u = __float_as_uint(v);
    hi = (short)(u >> 16);
    float l = v - __uint_as_float(u & 0xFFFF0000u);
    lo = (short)(__float_as_uint(l) >> 16);
}

// ---- mj fragment buffer: per molecule 24576 shorts (hi 0..12287, lo 12288..) ----
// [ch(4096)][f(32)][grp(8)][e]; value (jl, f): ch=jl>>5, grp=(jl>>3)&3, e=jl&7
__device__ __forceinline__ void mj_store(short* mjTg, int gr, int f, float v) {
    int mol = gr / NPER;
    int jl  = gr - mol * NPER;
    short hi, lo; split2(v, hi, lo);
    size_t mo = (size_t)mol * 24576;
    int off = (jl >> 5) * 4096 + f * 32 + ((jl >> 3) & 3) * 8 + (jl & 7);
    mjTg[mo + off] = hi;
    mjTg[mo + 12288 + off] = lo;
}

// activation planes: [16 rows][128 f] shorts, 16B-slot XOR swizzle
__device__ __forceinline__ int plane_idx(int r, int f) {
    int s = f >> 3;
    int sp = (s & 8) | ((s ^ (r & 7)) & 7);
    return r * 128 + sp * 8 + (f & 7);
}

__device__ __forceinline__ void plane_store(short* Ahi, short* Alo, int r, int f, float v) {
    int idx = plane_idx(r, f);
    short hi, lo; split2(v, hi, lo);
    Ahi[idx] = hi; Alo[idx] = lo;
}

// wave w stages ITS OWN 16KB quarter of a prepped 64KB matrix into LDS.
__device__ __forceinline__ void stage_w_wave(short* dstBase, const short* srcBase, int w, int lane) {
#pragma unroll
    for (int it = 0; it < 16; ++it) {
        int boff = w * 16384 + it * 1024;
        __builtin_amdgcn_global_load_lds(
            (const __attribute__((address_space(1))) unsigned int*)((const char*)srcBase + boff + lane * 16),
            (__attribute__((address_space(3))) unsigned int*)((char*)dstBase + boff),
            16, 0, 0);
    }
}

__device__ __forceinline__ void gemm_core(const short* Ahi, const short* Alo,
    const short* Wl, int lane, int fq0, f32x4 acc[2])
{
    const int r = lane & 15, h = lane >> 4;
    bf16x8 afh[4], afl[4];
#pragma unroll
    for (int kt = 0; kt < 4; ++kt) {
        int s = kt * 4 + h;
        int sp = (s & 8) | ((s ^ (r & 7)) & 7);
        afh[kt] = *(const bf16x8*)&Ahi[r * 128 + sp * 8];
        afl[kt] = *(const bf16x8*)&Alo[r * 128 + sp * 8];
    }
#pragma unroll
    for (int ft = 0; ft < 2; ++ft) {
        f32x4 a = {0.f, 0.f, 0.f, 0.f};
#pragma unroll
        for (int kt = 0; kt < 4; ++kt) {
            const short* bp = &Wl[((fq0 + ft) * 4 + kt) * 1024 + lane * 8];
            bf16x8 bh = *(const bf16x8*)bp;
            bf16x8 bl = *(const bf16x8*)(bp + 512);
            a = __builtin_amdgcn_mfma_f32_16x16x32_bf16(afh[kt], bl, a, 0, 0, 0);
            a = __builtin_amdgcn_mfma_f32_16x16x32_bf16(afl[kt], bh, a, 0, 0, 0);
            a = __builtin_amdgcn_mfma_f32_16x16x32_bf16(afh[kt], bh, a, 0, 0, 0);
        }
        acc[ft] = a;
    }
}

// ---------------- weight prep (unchanged) ----------------
__global__ __launch_bounds__(256) void k_prep(
    const float* __restrict__ Wi, const float* __restrict__ Wj,
    const float* __restrict__ rIW, const float* __restrict__ Wd,
    const float* __restrict__ rAW, const float* __restrict__ rOW,
    short* __restrict__ prepW)
{
    const int m = blockIdx.x, tid = threadIdx.x;
    const float* src;
    if (m == 65) src = Wi;
    else if (m == 66) src = Wj;
    else {
        int bb = m / 13, slot = m % 13;
        switch (slot) {
            case 0: case 1: case 2: case 3:
                src = rIW + (size_t)((bb * 2 + (slot >> 1)) * 2 + (slot & 1)) * 16384; break;
            case 4: src = Wd + (size_t)bb * 16384; break;
            case 5: case 6: case 7: case 8: {
                int ss = slot - 5;
                src = rAW + (size_t)((bb * 2 + (ss >> 1)) * 2 + (ss & 1)) * 16384; break;
            }
            case 9:  src = Wi + (size_t)((bb + 1 < 5) ? (bb + 1) : 0) * 16384; break;
            case 10: src = Wj + (size_t)((bb + 1 < 5) ? (bb + 1) : 0) * 16384; break;
            default: src = rOW + (size_t)(bb * 2 + (slot - 11)) * 16384; break;
        }
    }
    short* dst = prepW + (size_t)m * 32768;
#pragma unroll
    for (int i = 0; i < 8; ++i) {
        int tr = tid + i * 256;
        int ft = tr >> 8, kt = (tr >> 6) & 3, l = tr & 63;
        int f = ft * 16 + (l & 15);
        int k0 = kt * 32 + (l >> 4) * 8;
        bf16x8 hi8, lo8;
#pragma unroll
        for (int e = 0; e < 8; ++e) {
            float v = src[(size_t)(k0 + e) * FD + f];
            short hh, ll; split2(v, hh, ll);
            hi8[e] = hh; lo8[e] = ll;
        }
        size_t o = (size_t)(ft * 4 + kt) * 1024 + (size_t)l * 8;
        *(bf16x8*)&dst[o] = hi8;
        *(bf16x8*)&dst[o + 512] = lo8;
    }
}

// ---------------- k_first (unchanged) ----------------
__global__ __launch_bounds__(256) void k_first(
    const int* __restrict__ Za, const float* __restrict__ emb,
    const short* __restrict__ Wprep,
    const float* __restrict__ bi, const float* __restrict__ bj,
    float* __restrict__ X, float* __restrict__ MI, short* __restrict__ mjTg,
    float* __restrict__ Ea, float* __restrict__ Qa)
{
    __shared__ short Ahi[2048], Alo[2048];
    __shared__ short Wl[2][32768];
    const int tid = threadIdx.x, lane = tid & 63, w = tid >> 6;
    const int row0 = blockIdx.x * 16;
    const int fq0 = w * 2;
    const int col0 = w * 32 + (lane & 15), col1 = col0 + 16;
    const int hh = lane >> 4;

    stage_w_wave(Wl[0], Wprep + (size_t)65 * 32768, w, lane);   // Wi(0)

    for (int idx = tid; idx < 2048; idx += 256) {
        int rr = idx >> 7, f = idx & 127;
        float v = emb[(size_t)Za[row0 + rr] * FD + f];
        X[(size_t)(row0 + rr) * FD + f] = v;
        plane_store(Ahi, Alo, rr, f, sspf(v));
    }
    if (tid < 16) { Ea[row0 + tid] = 0.f; Qa[row0 + tid] = 0.f; }
    if ((row0 % NPER) == 0) {
        short* mb = mjTg + (size_t)(row0 / NPER) * 24576;
        for (int idx = tid; idx < 2048; idx += 256) {
            int f = idx >> 4, t = idx & 15;
            mb[8192 + f * 32 + 16 + t] = 0;
            mb[12288 + 8192 + f * 32 + 16 + t] = 0;
        }
    }
    __syncthreads();

    stage_w_wave(Wl[1], Wprep + (size_t)66 * 32768, w, lane);   // Wj(0)

    f32x4 acc[2];
    gemm_core(Ahi, Alo, Wl[0], lane, fq0, acc);
    {
        float b0 = bi[col0], b1 = bi[col1];
#pragma unroll
        for (int reg = 0; reg < 4; ++reg) {
            int rw = hh * 4 + reg;
            MI[(size_t)(row0 + rw) * FD + col0] = sspf(acc[0][reg] + b0);
            MI[(size_t)(row0 + rw) * FD + col1] = sspf(acc[1][reg] + b1);
        }
    }
    asm volatile("s_waitcnt vmcnt(0)" ::: "memory");
    gemm_core(Ahi, Alo, Wl[1], lane, fq0, acc);
    {
        float b0 = bj[col0], b1 = bj[col1];
#pragma unroll
        for (int reg = 0; reg < 4; ++reg) {
            int gr = row0 + hh * 4 + reg;
            mj_store(mjTg, gr, col0, sspf(acc[0][reg] + b0));
            mj_store(mjTg, gr, col1, sspf(acc[1][reg] + b1));
        }
    }
}

// ---------------- k_tail (bias loads hoisted before gemm) ----------------
__global__ __launch_bounds__(256) void k_tail(
    const float* __restrict__ M, float* __restrict__ X,
    const short* __restrict__ Wprep, int b,
    const float* __restrict__ rIb, const float* __restrict__ bd,
    const float* __restrict__ u, const float* __restrict__ rAb,
    const float* __restrict__ bi, const float* __restrict__ bj,
    const float* __restrict__ rOb, const float* __restrict__ Wout,
    const float* __restrict__ bout,
    float* __restrict__ MI, short* __restrict__ mjTg,
    float* __restrict__ Ea, float* __restrict__ Qa)
{
    __shared__ short Ahi[2048], Alo[2048];
    __shared__ short Wl[2][32768];
    __shared__ float eq[16][5][2];

    const int tid = threadIdx.x, lane = tid & 63, w = tid >> 6;
    const int row0 = blockIdx.x * 16;
    const int NG = (b < 4) ? 13 : 11;
    const int fq0 = w * 2;
    const int col0 = w * 32 + (lane & 15), col1 = col0 + 16;
    const int hh = lane >> 4;

    auto lgOf = [&](int gg) { return (b < 4 || gg < 9) ? gg : gg + 2; };

    stage_w_wave(Wl[0], Wprep + (size_t)(b * 13 + lgOf(0)) * 32768, w, lane);

    float vreg[2][4], xreg[2][4];
#pragma unroll
    for (int reg = 0; reg < 4; ++reg) {
        int rw = hh * 4 + reg;
        vreg[0][reg] = M[(size_t)(row0 + rw) * FD + col0];
        vreg[1][reg] = M[(size_t)(row0 + rw) * FD + col1];
        xreg[0][reg] = X[(size_t)(row0 + rw) * FD + col0];
        xreg[1][reg] = X[(size_t)(row0 + rw) * FD + col1];
    }
    for (int idx = tid; idx < 2048; idx += 256) {
        int rr = idx >> 7, f = idx & 127;
        plane_store(Ahi, Alo, rr, f, sspf(M[(size_t)(row0 + rr) * FD + f]));
    }
    __syncthreads();

    f32x4 acc[2];
    for (int g = 0; g < NG; ++g) {
        const int cur = g & 1;
        if (g > 0) {
            asm volatile("s_waitcnt lgkmcnt(0)\n\ts_barrier" ::: "memory");
            asm volatile("s_waitcnt vmcnt(0)" ::: "memory");
        }
        if (g + 1 < NG)
            stage_w_wave(Wl[cur ^ 1], Wprep + (size_t)(b * 13 + lgOf(g + 1)) * 32768, w, lane);

        // hoist bias/u loads BEFORE gemm so their latency hides under MFMAs
        int lg = lgOf(g);
        const float* bptr;
        switch (lg) {
            case 0:  bptr = rIb + ((size_t)(b * 2 + 0) * 2 + 0) * FD; break;
            case 1:  bptr = rIb + ((size_t)(b * 2 + 0) * 2 + 1) * FD; break;
            case 2:  bptr = rIb + ((size_t)(b * 2 + 1) * 2 + 0) * FD; break;
            case 3:  bptr = rIb + ((size_t)(b * 2 + 1) * 2 + 1) * FD; break;
            case 4:  bptr = bd + (size_t)b * FD; break;
            case 5:  bptr = rAb + ((size_t)(b * 2 + 0) * 2 + 0) * FD; break;
            case 6:  bptr = rAb + ((size_t)(b * 2 + 0) * 2 + 1) * FD; break;
            case 7:  bptr = rAb + ((size_t)(b * 2 + 1) * 2 + 0) * FD; break;
            case 8:  bptr = rAb + ((size_t)(b * 2 + 1) * 2 + 1) * FD; break;
            case 9:  bptr = bi + (size_t)(b + 1) * FD; break;
            case 10: bptr = bj + (size_t)(b + 1) * FD; break;
            case 11: bptr = rOb + (size_t)(b * 2 + 0) * FD; break;
            default: bptr = rOb + (size_t)(b * 2 + 1) * FD; break;
        }
        float bv0 = bptr[col0], bv1 = bptr[col1];
        float uv0 = 0.f, uv1 = 0.f;
        if (lg == 4) { uv0 = u[(size_t)b * FD + col0]; uv1 = u[(size_t)b * FD + col1]; }

        gemm_core(Ahi, Alo, Wl[cur], lane, fq0, acc);

        asm volatile("s_waitcnt lgkmcnt(0)\n\ts_barrier" ::: "memory");

        const bool isT = (lg == 0) | (lg == 2) | (lg == 5) | (lg == 7) | (lg == 11);
        const bool isV = (lg == 1) | (lg == 3) | (lg == 6) | (lg == 8) | (lg == 12);
        if (isT) {
#pragma unroll
            for (int reg = 0; reg < 4; ++reg) {
                int rw = hh * 4 + reg;
                plane_store(Ahi, Alo, rw, col0, sspf(acc[0][reg] + bv0));
                plane_store(Ahi, Alo, rw, col1, sspf(acc[1][reg] + bv1));
            }
        } else if (isV) {
#pragma unroll
            for (int reg = 0; reg < 4; ++reg) {
                int rw = hh * 4 + reg;
                float nv0 = acc[0][reg] + bv0 + vreg[0][reg];
                float nv1 = acc[1][reg] + bv1 + vreg[1][reg];
                vreg[0][reg] = nv0; vreg[1][reg] = nv1;
                if (lg != 12) {
                    plane_store(Ahi, Alo, rw, col0, sspf(nv0));
                    plane_store(Ahi, Alo, rw, col1, sspf(nv1));
                }
                if (lg == 8) {
                    X[(size_t)(row0 + rw) * FD + col0] = nv0;
                    X[(size_t)(row0 + rw) * FD + col1] = nv1;
                }
            }
        } else if (lg == 4) {
#pragma unroll
            for (int reg = 0; reg < 4; ++reg) {
                int rw = hh * 4 + reg;
                float nv0 = acc[0][reg] + bv0 + uv0 * xreg[0][reg];
                float nv1 = acc[1][reg] + bv1 + uv1 * xreg[1][reg];
                vreg[0][reg] = nv0; vreg[1][reg] = nv1;
                plane_store(Ahi, Alo, rw, col0, sspf(nv0));
                plane_store(Ahi, Alo, rw, col1, sspf(nv1));
            }
        } else if (lg == 9) {
#pragma unroll
            for (int reg = 0; reg < 4; ++reg) {
                int rw = hh * 4 + reg;
                MI[(size_t)(row0 + rw) * FD + col0] = sspf(acc[0][reg] + bv0);
                MI[(size_t)(row0 + rw) * FD + col1] = sspf(acc[1][reg] + bv1);
            }
        } else {
#pragma unroll
            for (int reg = 0; reg < 4; ++reg) {
                int gr = row0 + hh * 4 + reg;
                mj_store(mjTg, gr, col0, sspf(acc[0][reg] + bv0));
                mj_store(mjTg, gr, col1, sspf(acc[1][reg] + bv1));
            }
        }
    }
    float pe[4], pq[4];
#pragma unroll
    for (int reg = 0; reg < 4; ++reg) {
        float s0 = sspf(vreg[0][reg]), s1 = sspf(vreg[1][reg]);
        pe[reg] = s0 * Wout[col0 * 2 + 0] + s1 * Wout[col1 * 2 + 0];
        pq[reg] = s0 * Wout[col0 * 2 + 1] + s1 * Wout[col1 * 2 + 1];
#pragma unroll
        for (int mk = 1; mk < 16; mk <<= 1) {
            pe[reg] += __shfl_xor(pe[reg], mk);
            pq[reg] += __shfl_xor(pq[reg], mk);
        }
        if ((lane & 15) == 0) {
            eq[hh * 4 + reg][w][0] = pe[reg];
            eq[hh * 4 + reg][w][1] = pq[reg];
        }
    }
    __syncthreads();
    if (tid < 16) {
        float e = eq[tid][0][0] + eq[tid][1][0] + eq[tid][2][0] + eq[tid][3][0];
        float q = eq[tid][0][1] + eq[tid][1][1] + eq[tid][2][1] + eq[tid][3][1];
        Ea[row0 + tid] += e + bout[0];
        Qa[row0 + tid] += q + bout[1];
    }
}

// ---------------- k_msg v3: LDS-staged B via global_load_lds, 8 atoms/block ----------------
// One wave = one atom, acc[4][8] (full f range). Whole-molecule fragment buffer
// (48KB, already frag-ordered -> linear LDS dest) staged with full MLP; B reads
// become conflict-free ds_read_b128.
__global__ __launch_bounds__(512, 2) void k_msg(
    const float* __restrict__ Ra, const float* __restrict__ MI,
    const short* __restrict__ mjTg, const float* __restrict__ centers,
    const float* __restrict__ widths, const float* __restrict__ Wrbf,
    float* __restrict__ MOUT)
{
    __shared__ short Bf[24576];         // 48 KB: hi [0..12287], lo [12288..24575]
    __shared__ float Wt[8192];          // 32 KB
    __shared__ float px[NPER], py[NPER], pz[NPER];

    const int tid  = threadIdx.x;
    const int lane = tid & 63;
    const int w    = tid >> 6;           // 8 waves
    const int mol  = blockIdx.x / (NPER / 8);
    const int ig   = blockIdx.x % (NPER / 8);
    const int base = mol * NPER;
    const int i    = ig * 8 + w;         // this wave's atom

    const int col = lane & 15;
    const int grp = lane >> 4;

    // stage fragment buffer: wave w covers bytes [w*6144, (w+1)*6144)
    {
        const char* src = (const char*)mjTg + (size_t)mol * 49152 + w * 6144 + lane * 16;
        char* dst = (char*)Bf + w * 6144;
#pragma unroll
        for (int it = 0; it < 6; ++it) {
            __builtin_amdgcn_global_load_lds(
                (const __attribute__((address_space(1))) unsigned int*)(src + it * 1024),
                (__attribute__((address_space(3))) unsigned int*)(dst + it * 1024),
                16, 0, 0);
        }
    }
    // Wt: [k>>2][f][k&3] fp32 (2-way-free b128 reads in epilogue)
    for (int idx = tid; idx < KR * FD; idx += 512) {
        int k = idx >> 7, f = idx & 127;
        Wt[(k >> 2) * 512 + f * 4 + (k & 3)] = Wrbf[idx];
    }
    if (tid < NPER) {
        px[tid] = Ra[(size_t)(base + tid) * 3 + 0];
        py[tid] = Ra[(size_t)(base + tid) * 3 + 1];
        pz[tid] = Ra[(size_t)(base + tid) * 3 + 2];
    }

    float cent[4], wid[4];
#pragma unroll
    for (int kt = 0; kt < 4; ++kt) {
        cent[kt] = centers[kt * 16 + col];
        wid[kt]  = widths[kt * 16 + col];
    }

    f32x4 acc[4][8];
#pragma unroll
    for (int kt = 0; kt < 4; ++kt)
#pragma unroll
        for (int ft = 0; ft < 8; ++ft)
            acc[kt][ft] = (f32x4){0.f, 0.f, 0.f, 0.f};

    __syncthreads();   // drains vmcnt+lgkm: Bf, Wt, positions all ready

    const float xi = px[i], yi = py[i], zi = pz[i];

    for (int ch = 0; ch < 3; ++ch) {
        // A fragments (rbf) in-register
        bf16x8 Ahi[4], Alo[4];
#pragma unroll
        for (int e = 0; e < 8; ++e) {
            int jg = ch * 32 + grp * 8 + e;
            float ed = 0.f, cut = 0.f;
            if (jg < NPER) {
                float dx = px[jg] - xi, dy = py[jg] - yi, dz = pz[jg] - zi;
                float d = sqrtf(dx * dx + dy * dy + dz * dz);
                ed = __expf(-d);
                if (jg != i && d < SR_CUT_C) {
                    float xr = d * (1.0f / SR_CUT_C);
                    float xr2 = xr * xr, xr3 = xr2 * xr;
                    cut = 1.0f - xr3 * (6.0f * xr2 - 15.0f * xr + 10.0f);
                }
            }
#pragma unroll
            for (int kt = 0; kt < 4; ++kt) {
                float t = ed - cent[kt];
                float val = cut * __expf(-wid[kt] * t * t);
                unsigned uv = __float_as_uint(val);
                Ahi[kt][e] = (short)(uv >> 16);
                float lv = val - __uint_as_float(uv & 0xFFFF0000u);
                Alo[kt][e] = (short)(__float_as_uint(lv) >> 16);
            }
        }

        const int cb = ch * 4096 + col * 32 + grp * 8;
#pragma unroll
        for (int ft = 0; ft < 8; ++ft) {
            bf16x8 bhi = *(const bf16x8*)&Bf[cb + ft * 512];
            bf16x8 blo = *(const bf16x8*)&Bf[12288 + cb + ft * 512];
            __builtin_amdgcn_s_setprio(1);
#pragma unroll
            for (int kt = 0; kt < 4; ++kt) {
                acc[kt][ft] = __builtin_amdgcn_mfma_f32_16x16x32_bf16(Ahi[kt], bhi, acc[kt][ft], 0, 0, 0);
                acc[kt][ft] = __builtin_amdgcn_mfma_f32_16x16x32_bf16(Alo[kt], bhi, acc[kt][ft], 0, 0, 0);
                acc[kt][ft] = __builtin_amdgcn_mfma_f32_16x16x32_bf16(Ahi[kt], blo, acc[kt][ft], 0, 0, 0);
            }
            __builtin_amdgcn_s_setprio(0);
        }
    }

    // epilogue: part[ft] = sum_k Wrbf[k,f] * T[k,f]
    float part[8];
#pragma unroll
    for (int ft = 0; ft < 8; ++ft) part[ft] = 0.f;
#pragma unroll
    for (int kt = 0; kt < 4; ++kt) {
        const float* wrow = &Wt[(kt * 4 + grp) * 512 + col * 4];
#pragma unroll
        for (int ft = 0; ft < 8; ++ft) {
            float4 w4 = *(const float4*)(wrow + ft * 64);
            part[ft] += acc[kt][ft].x * w4.x + acc[kt][ft].y * w4.y
                      + acc[kt][ft].z * w4.z + acc[kt][ft].w * w4.w;
        }
    }
#pragma unroll
    for (int ft = 0; ft < 8; ++ft) {
        part[ft] += __shfl_xor(part[ft], 16);
        part[ft] += __shfl_xor(part[ft], 32);
    }
    float p0 = (grp == 0) ? part[0] : (grp == 1) ? part[1] : (grp == 2) ? part[2] : part[3];
    float p1 = (grp == 0) ? part[4] : (grp == 1) ? part[5] : (grp == 2) ? part[6] : part[7];
    const size_t go = (size_t)(base + i) * FD;
    MOUT[go + lane]      = MI[go + lane] + p0;
    MOUT[go + 64 + lane] = MI[go + 64 + lane] + p1;
}

// ---------------- finale (unchanged) ----------------
__global__ __launch_bounds__(256) void k_final(
    const int* __restrict__ Za, const float* __restrict__ Ra,
    const float* __restrict__ Escale, const float* __restrict__ Eshift,
    const float* __restrict__ Qscale, const float* __restrict__ Qshift,
    const float* __restrict__ Ea, const float* __restrict__ Qa,
    float* __restrict__ out)
{
    __shared__ float qs[NPER], es[NPER], px[NPER], py[NPER], pz[NPER];
    __shared__ float red[256];
    const int mol = blockIdx.x, t = threadIdx.x;
    float q = 0.f;
    if (t < NPER) {
        int a = mol * NPER + t;
        int z = Za[a];
        es[t] = Escale[z] * Ea[a] + Eshift[z];
        q = Qscale[z] * Qa[a] + Qshift[z];
        px[t] = Ra[(size_t)a * 3 + 0];
        py[t] = Ra[(size_t)a * 3 + 1];
        pz[t] = Ra[(size_t)a * 3 + 2];
    }
    red[t] = q;
    __syncthreads();
    for (int s = 128; s > 0; s >>= 1) {
        if (t < s) red[t] += red[t + s];
        __syncthreads();
    }
    float qavg = red[0] / (float)NPER;
    __syncthreads();
    if (t < NPER) qs[t] = q - qavg;
    red[t] = 0.f;
    __syncthreads();

    float local = 0.f;
    const float c = SR_CUT_C * 0.5f;
    for (int p = t; p < NPER * NPER; p += 256) {
        int i = p / NPER, j = p % NPER;
        if (i == j) continue;
        float dx = px[i] - px[j], dy = py[i] - py[j], dz = pz[i] - pz[j];
        float d2 = dx * dx + dy * dy + dz * dz;
        float d = sqrtf(d2);
        float dS = sqrtf(d2 + 1.0f);
        float sw;
        if (d < c) {
            float xs = d / c;
            float xs2 = xs * xs, xs3 = xs2 * xs;
            sw = xs3 * (6.0f * xs2 - 15.0f * xs + 10.0f);
        } else {
            sw = 1.0f;
        }
        local += KEHALF_C * qs[i] * qs[j] * ((1.0f - sw) / dS + sw / d);
    }
    for (int a = t; a < NPER; a += 256) local += es[a];
    red[t] = local;
    __syncthreads();
    for (int s = 128; s > 0; s >>= 1) {
        if (t < s) red[t] += red[t + s];
        __syncthreads();
    }
    if (t == 0) out[mol] = red[0];
}

extern "C" void kernel_launch(void* const* d_in, const int* in_sizes, int n_in,
                              void* d_out, int out_size, void* d_ws, size_t ws_size,
                              hipStream_t stream)
{
    (void)in_sizes; (void)n_in; (void)out_size; (void)ws_size;

    const int*   Za     = (const int*)d_in[0];
    const float* Ra     = (const float*)d_in[1];
    const float* emb    = (const float*)d_in[5];
    const float* rbfc   = (const float*)d_in[6];
    const float* rbfw   = (const float*)d_in[7];
    const float* Wrbf   = (const float*)d_in[8];
    const float* Wi     = (const float*)d_in[9];
    const float* bi     = (const float*)d_in[10];
    const float* Wj     = (const float*)d_in[11];
    const float* bj     = (const float*)d_in[12];
    const float* rIW    = (const float*)d_in[13];
    const float* rIb    = (const float*)d_in[14];
    const float* Wd     = (const float*)d_in[15];
    const float* bd     = (const float*)d_in[16];
    const float* u      = (const float*)d_in[17];
    const float* rAW    = (const float*)d_in[18];
    const float* rAb    = (const float*)d_in[19];
    const float* rOW    = (const float*)d_in[20];
    const float* rOb    = (const float*)d_in[21];
    const float* Wout   = (const float*)d_in[22];
    const float* bout   = (const float*)d_in[23];
    const float* Escale = (const float*)d_in[24];
    const float* Eshift = (const float*)d_in[25];
    const float* Qscale = (const float*)d_in[26];
    const float* Qshift = (const float*)d_in[27];
    float* outp = (float*)d_out;

    float* ws = (float*)d_ws;
    const size_t NF = (size_t)NATOM * FD;
    float* x  = ws;
    float* mi = ws + NF;
    float* m  = ws + 2 * NF;
    float* Ea = ws + 3 * NF;
    float* Qa = Ea + NATOM;
    short* prepW = (short*)(ws + 3 * NF + 2 * NATOM);
    short* mjTg  = prepW + (size_t)67 * 32768;

    k_prep<<<67, 256, 0, stream>>>(Wi, Wj, rIW, Wd, rAW, rOW, prepW);
    k_first<<<NATOM / 16, 256, 0, stream>>>(Za, emb, prepW, bi, bj, x, mi, mjTg, Ea, Qa);

    for (int b = 0; b < NBLOCK; ++b) {
        k_msg<<<NMOL * (NPER / 8), 512, 0, stream>>>(
            Ra, mi, mjTg, rbfc, rbfw, Wrbf + (size_t)b * KR * FD, m);
        k_tail<<<NATOM / 16, 256, 0, stream>>>(
            m, x, prepW, b, rIb, bd, u, rAb, bi, bj, rOb,
            Wout + (size_t)b * FD * 2, bout + b * 2, mi, mjTg, Ea, Qa);
    }

    k_final<<<NMOL, 256, 0, stream>>>(Za, Ra, Escale, Eshift, Qscale, Qshift, Ea, Qa, outp);
}

// Round 11
// 342.876 us; speedup vs baseline: 1.2495x; 1.0165x over previous
//
#include <hip/hip_runtime.h>

#define NATOM 3840
#define NMOL 48
#define NPER 80
#define FD 128
#define KR 64
#define NBLOCK 5

constexpr float SR_CUT_C = 10.0f;
constexpr float KEHALF_C = 7.199822675975274f;
constexpr float LN2_C    = 0.6931471805599453f;

using bf16x8 = __attribute__((ext_vector_type(8))) short;
using f32x4  = __attribute__((ext_vector_type(4))) float;

__device__ __forceinline__ float sspf(float x) {
    return fmaxf(x, 0.0f) + __logf(1.0f + __expf(-fabsf(x))) - LN2_C;
}

// truncation split: v ~= hi + lo (both bf16), |err| <~ 2^-16 |v|
__device__ __forceinline__ void split2(float v, short& hi, short& lo) {
    unsigned u = __float_as_uint(v);
    hi = (short)(u >> 16);
    float l = v - __uint_as_float(u & 0xFFFF0000u);
    lo = (short)(__float_as_uint(l) >> 16);
}

// ---- mj fragment buffer: per molecule 24576 shorts (hi 0..12287, lo 12288..) ----
// [ch(4096)][f(32)][grp(8)][e]; value (jl, f): ch=jl>>5, grp=(jl>>3)&3, e=jl&7
__device__ __forceinline__ void mj_store(short* mjTg, int gr, int f, float v) {
    int mol = gr / NPER;
    int jl  = gr - mol * NPER;
    short hi, lo; split2(v, hi, lo);
    size_t mo = (size_t)mol * 24576;
    int off = (jl >> 5) * 4096 + f * 32 + ((jl >> 3) & 3) * 8 + (jl & 7);
    mjTg[mo + off] = hi;
    mjTg[mo + 12288 + off] = lo;
}

// activation planes: [16 rows][128 f] shorts, 16B-slot XOR swizzle
__device__ __forceinline__ int plane_idx(int r, int f) {
    int s = f >> 3;
    int sp = (s & 8) | ((s ^ (r & 7)) & 7);
    return r * 128 + sp * 8 + (f & 7);
}

__device__ __forceinline__ void plane_store(short* Ahi, short* Alo, int r, int f, float v) {
    int idx = plane_idx(r, f);
    short hi, lo; split2(v, hi, lo);
    Ahi[idx] = hi; Alo[idx] = lo;
}

// 4-wave variant: wave stages its 16KB quarter (fq = 2w,2w+1)
__device__ __forceinline__ void stage_w_wave(short* dstBase, const short* srcBase, int w, int lane) {
#pragma unroll
    for (int it = 0; it < 16; ++it) {
        int boff = w * 16384 + it * 1024;
        __builtin_amdgcn_global_load_lds(
            (const __attribute__((address_space(1))) unsigned int*)((const char*)srcBase + boff + lane * 16),
            (__attribute__((address_space(3))) unsigned int*)((char*)dstBase + boff),
            16, 0, 0);
    }
}

// 8-wave variant: wave stages its 8KB eighth (fq = w)
__device__ __forceinline__ void stage_w_wave8(short* dstBase, const short* srcBase, int w, int lane) {
#pragma unroll
    for (int it = 0; it < 8; ++it) {
        int boff = w * 8192 + it * 1024;
        __builtin_amdgcn_global_load_lds(
            (const __attribute__((address_space(1))) unsigned int*)((const char*)srcBase + boff + lane * 16),
            (__attribute__((address_space(3))) unsigned int*)((char*)dstBase + boff),
            16, 0, 0);
    }
}

// 2-ft gemm (k_first): C[16 x 32] = planes @ W[:, fq0*16 .. fq0*16+31]
__device__ __forceinline__ void gemm_core(const short* Ahi, const short* Alo,
    const short* Wl, int lane, int fq0, f32x4 acc[2])
{
    const int r = lane & 15, h = lane >> 4;
    bf16x8 afh[4], afl[4];
#pragma unroll
    for (int kt = 0; kt < 4; ++kt) {
        int s = kt * 4 + h;
        int sp = (s & 8) | ((s ^ (r & 7)) & 7);
        afh[kt] = *(const bf16x8*)&Ahi[r * 128 + sp * 8];
        afl[kt] = *(const bf16x8*)&Alo[r * 128 + sp * 8];
    }
#pragma unroll
    for (int ft = 0; ft < 2; ++ft) {
        f32x4 a = {0.f, 0.f, 0.f, 0.f};
#pragma unroll
        for (int kt = 0; kt < 4; ++kt) {
            const short* bp = &Wl[((fq0 + ft) * 4 + kt) * 1024 + lane * 8];
            bf16x8 bh = *(const bf16x8*)bp;
            bf16x8 bl = *(const bf16x8*)(bp + 512);
            a = __builtin_amdgcn_mfma_f32_16x16x32_bf16(afh[kt], bl, a, 0, 0, 0);
            a = __builtin_amdgcn_mfma_f32_16x16x32_bf16(afl[kt], bh, a, 0, 0, 0);
            a = __builtin_amdgcn_mfma_f32_16x16x32_bf16(afh[kt], bh, a, 0, 0, 0);
        }
        acc[ft] = a;
    }
}

// 1-ft gemm (k_tail 8-wave): C[16 x 16] = planes @ W[:, fq*16 .. fq*16+15]
__device__ __forceinline__ void gemm_core1(const short* Ahi, const short* Alo,
    const short* Wl, int lane, int fq, f32x4& acc)
{
    const int r = lane & 15, h = lane >> 4;
    bf16x8 afh[4], afl[4];
#pragma unroll
    for (int kt = 0; kt < 4; ++kt) {
        int s = kt * 4 + h;
        int sp = (s & 8) | ((s ^ (r & 7)) & 7);
        afh[kt] = *(const bf16x8*)&Ahi[r * 128 + sp * 8];
        afl[kt] = *(const bf16x8*)&Alo[r * 128 + sp * 8];
    }
    f32x4 a = {0.f, 0.f, 0.f, 0.f};
#pragma unroll
    for (int kt = 0; kt < 4; ++kt) {
        const short* bp = &Wl[(fq * 4 + kt) * 1024 + lane * 8];
        bf16x8 bh = *(const bf16x8*)bp;
        bf16x8 bl = *(const bf16x8*)(bp + 512);
        a = __builtin_amdgcn_mfma_f32_16x16x32_bf16(afh[kt], bl, a, 0, 0, 0);
        a = __builtin_amdgcn_mfma_f32_16x16x32_bf16(afl[kt], bh, a, 0, 0, 0);
        a = __builtin_amdgcn_mfma_f32_16x16x32_bf16(afh[kt], bh, a, 0, 0, 0);
    }
    acc = a;
}

// ---------------- weight prep (unchanged) ----------------
__global__ __launch_bounds__(256) void k_prep(
    const float* __restrict__ Wi, const float* __restrict__ Wj,
    const float* __restrict__ rIW, const float* __restrict__ Wd,
    const float* __restrict__ rAW, const float* __restrict__ rOW,
    short* __restrict__ prepW)
{
    const int m = blockIdx.x, tid = threadIdx.x;
    const float* src;
    if (m == 65) src = Wi;
    else if (m == 66) src = Wj;
    else {
        int bb = m / 13, slot = m % 13;
        switch (slot) {
            case 0: case 1: case 2: case 3:
                src = rIW + (size_t)((bb * 2 + (slot >> 1)) * 2 + (slot & 1)) * 16384; break;
            case 4: src = Wd + (size_t)bb * 16384; break;
            case 5: case 6: case 7: case 8: {
                int ss = slot - 5;
                src = rAW + (size_t)((bb * 2 + (ss >> 1)) * 2 + (ss & 1)) * 16384; break;
            }
            case 9:  src = Wi + (size_t)((bb + 1 < 5) ? (bb + 1) : 0) * 16384; break;
            case 10: src = Wj + (size_t)((bb + 1 < 5) ? (bb + 1) : 0) * 16384; break;
            default: src = rOW + (size_t)(bb * 2 + (slot - 11)) * 16384; break;
        }
    }
    short* dst = prepW + (size_t)m * 32768;
#pragma unroll
    for (int i = 0; i < 8; ++i) {
        int tr = tid + i * 256;
        int ft = tr >> 8, kt = (tr >> 6) & 3, l = tr & 63;
        int f = ft * 16 + (l & 15);
        int k0 = kt * 32 + (l >> 4) * 8;
        bf16x8 hi8, lo8;
#pragma unroll
        for (int e = 0; e < 8; ++e) {
            float v = src[(size_t)(k0 + e) * FD + f];
            short hh, ll; split2(v, hh, ll);
            hi8[e] = hh; lo8[e] = ll;
        }
        size_t o = (size_t)(ft * 4 + kt) * 1024 + (size_t)l * 8;
        *(bf16x8*)&dst[o] = hi8;
        *(bf16x8*)&dst[o + 512] = lo8;
    }
}

// ---------------- k_first (unchanged) ----------------
__global__ __launch_bounds__(256) void k_first(
    const int* __restrict__ Za, const float* __restrict__ emb,
    const short* __restrict__ Wprep,
    const float* __restrict__ bi, const float* __restrict__ bj,
    float* __restrict__ X, float* __restrict__ MI, short* __restrict__ mjTg,
    float* __restrict__ Ea, float* __restrict__ Qa)
{
    __shared__ short Ahi[2048], Alo[2048];
    __shared__ short Wl[2][32768];
    const int tid = threadIdx.x, lane = tid & 63, w = tid >> 6;
    const int row0 = blockIdx.x * 16;
    const int fq0 = w * 2;
    const int col0 = w * 32 + (lane & 15), col1 = col0 + 16;
    const int hh = lane >> 4;

    stage_w_wave(Wl[0], Wprep + (size_t)65 * 32768, w, lane);   // Wi(0)

    for (int idx = tid; idx < 2048; idx += 256) {
        int rr = idx >> 7, f = idx & 127;
        float v = emb[(size_t)Za[row0 + rr] * FD + f];
        X[(size_t)(row0 + rr) * FD + f] = v;
        plane_store(Ahi, Alo, rr, f, sspf(v));
    }
    if (tid < 16) { Ea[row0 + tid] = 0.f; Qa[row0 + tid] = 0.f; }
    if ((row0 % NPER) == 0) {
        short* mb = mjTg + (size_t)(row0 / NPER) * 24576;
        for (int idx = tid; idx < 2048; idx += 256) {
            int f = idx >> 4, t = idx & 15;
            mb[8192 + f * 32 + 16 + t] = 0;
            mb[12288 + 8192 + f * 32 + 16 + t] = 0;
        }
    }
    __syncthreads();

    stage_w_wave(Wl[1], Wprep + (size_t)66 * 32768, w, lane);   // Wj(0)

    f32x4 acc[2];
    gemm_core(Ahi, Alo, Wl[0], lane, fq0, acc);
    {
        float b0 = bi[col0], b1 = bi[col1];
#pragma unroll
        for (int reg = 0; reg < 4; ++reg) {
            int rw = hh * 4 + reg;
            MI[(size_t)(row0 + rw) * FD + col0] = sspf(acc[0][reg] + b0);
            MI[(size_t)(row0 + rw) * FD + col1] = sspf(acc[1][reg] + b1);
        }
    }
    asm volatile("s_waitcnt vmcnt(0)" ::: "memory");
    gemm_core(Ahi, Alo, Wl[1], lane, fq0, acc);
    {
        float b0 = bj[col0], b1 = bj[col1];
#pragma unroll
        for (int reg = 0; reg < 4; ++reg) {
            int gr = row0 + hh * 4 + reg;
            mj_store(mjTg, gr, col0, sspf(acc[0][reg] + b0));
            mj_store(mjTg, gr, col1, sspf(acc[1][reg] + b1));
        }
    }
}

// ---------------- k_tail: 8 waves, one fq-quarter (16 cols) per wave ----------------
__global__ __launch_bounds__(512) void k_tail(
    const float* __restrict__ M, float* __restrict__ X,
    const short* __restrict__ Wprep, int b,
    const float* __restrict__ rIb, const float* __restrict__ bd,
    const float* __restrict__ u, const float* __restrict__ rAb,
    const float* __restrict__ bi, const float* __restrict__ bj,
    const float* __restrict__ rOb, const float* __restrict__ Wout,
    const float* __restrict__ bout,
    float* __restrict__ MI, short* __restrict__ mjTg,
    float* __restrict__ Ea, float* __restrict__ Qa)
{
    __shared__ short Ahi[2048], Alo[2048];
    __shared__ short Wl[2][32768];
    __shared__ float eq[16][8][2];

    const int tid = threadIdx.x, lane = tid & 63, w = tid >> 6;  // 8 waves
    const int row0 = blockIdx.x * 16;
    const int NG = (b < 4) ? 13 : 11;
    const int fq = w;
    const int col0 = w * 16 + (lane & 15);
    const int hh = lane >> 4;

    auto lgOf = [&](int gg) { return (b < 4 || gg < 9) ? gg : gg + 2; };

    stage_w_wave8(Wl[0], Wprep + (size_t)(b * 13 + lgOf(0)) * 32768, w, lane);

    float vreg[4], xreg[4];
#pragma unroll
    for (int reg = 0; reg < 4; ++reg) {
        int rw = hh * 4 + reg;
        vreg[reg] = M[(size_t)(row0 + rw) * FD + col0];
        xreg[reg] = X[(size_t)(row0 + rw) * FD + col0];
    }
    for (int idx = tid; idx < 2048; idx += 512) {
        int rr = idx >> 7, f = idx & 127;
        plane_store(Ahi, Alo, rr, f, sspf(M[(size_t)(row0 + rr) * FD + f]));
    }
    __syncthreads();

    f32x4 acc;
    for (int g = 0; g < NG; ++g) {
        const int cur = g & 1;
        if (g > 0) {
            asm volatile("s_waitcnt lgkmcnt(0)\n\ts_barrier" ::: "memory");
            asm volatile("s_waitcnt vmcnt(0)" ::: "memory");
        }
        if (g + 1 < NG)
            stage_w_wave8(Wl[cur ^ 1], Wprep + (size_t)(b * 13 + lgOf(g + 1)) * 32768, w, lane);

        // hoist bias/u loads BEFORE gemm so their latency hides under MFMAs
        int lg = lgOf(g);
        const float* bptr;
        switch (lg) {
            case 0:  bptr = rIb + ((size_t)(b * 2 + 0) * 2 + 0) * FD; break;
            case 1:  bptr = rIb + ((size_t)(b * 2 + 0) * 2 + 1) * FD; break;
            case 2:  bptr = rIb + ((size_t)(b * 2 + 1) * 2 + 0) * FD; break;
            case 3:  bptr = rIb + ((size_t)(b * 2 + 1) * 2 + 1) * FD; break;
            case 4:  bptr = bd + (size_t)b * FD; break;
            case 5:  bptr = rAb + ((size_t)(b * 2 + 0) * 2 + 0) * FD; break;
            case 6:  bptr = rAb + ((size_t)(b * 2 + 0) * 2 + 1) * FD; break;
            case 7:  bptr = rAb + ((size_t)(b * 2 + 1) * 2 + 0) * FD; break;
            case 8:  bptr = rAb + ((size_t)(b * 2 + 1) * 2 + 1) * FD; break;
            case 9:  bptr = bi + (size_t)(b + 1) * FD; break;
            case 10: bptr = bj + (size_t)(b + 1) * FD; break;
            case 11: bptr = rOb + (size_t)(b * 2 + 0) * FD; break;
            default: bptr = rOb + (size_t)(b * 2 + 1) * FD; break;
        }
        float bv0 = bptr[col0];
        float uv0 = 0.f;
        if (lg == 4) uv0 = u[(size_t)b * FD + col0];

        gemm_core1(Ahi, Alo, Wl[cur], lane, fq, acc);

        asm volatile("s_waitcnt lgkmcnt(0)\n\ts_barrier" ::: "memory");

        const bool isT = (lg == 0) | (lg == 2) | (lg == 5) | (lg == 7) | (lg == 11);
        const bool isV = (lg == 1) | (lg == 3) | (lg == 6) | (lg == 8) | (lg == 12);
        if (isT) {
#pragma unroll
            for (int reg = 0; reg < 4; ++reg)
                plane_store(Ahi, Alo, hh * 4 + reg, col0, sspf(acc[reg] + bv0));
        } else if (isV) {
#pragma unroll
            for (int reg = 0; reg < 4; ++reg) {
                int rw = hh * 4 + reg;
                float nv0 = acc[reg] + bv0 + vreg[reg];
                vreg[reg] = nv0;
                if (lg != 12) plane_store(Ahi, Alo, rw, col0, sspf(nv0));
                if (lg == 8)  X[(size_t)(row0 + rw) * FD + col0] = nv0;
            }
        } else if (lg == 4) {
#pragma unroll
            for (int reg = 0; reg < 4; ++reg) {
                float nv0 = acc[reg] + bv0 + uv0 * xreg[reg];
                vreg[reg] = nv0;
                plane_store(Ahi, Alo, hh * 4 + reg, col0, sspf(nv0));
            }
        } else if (lg == 9) {
#pragma unroll
            for (int reg = 0; reg < 4; ++reg)
                MI[(size_t)(row0 + hh * 4 + reg) * FD + col0] = sspf(acc[reg] + bv0);
        } else {   // lg == 10: mj for next block -> fragment layout
#pragma unroll
            for (int reg = 0; reg < 4; ++reg)
                mj_store(mjTg, row0 + hh * 4 + reg, col0, sspf(acc[reg] + bv0));
        }
    }
    // output projection: e/q = ssp(o) @ Wout + bout
    float pe[4], pq[4];
#pragma unroll
    for (int reg = 0; reg < 4; ++reg) {
        float s0 = sspf(vreg[reg]);
        pe[reg] = s0 * Wout[col0 * 2 + 0];
        pq[reg] = s0 * Wout[col0 * 2 + 1];
#pragma unroll
        for (int mk = 1; mk < 16; mk <<= 1) {
            pe[reg] += __shfl_xor(pe[reg], mk);
            pq[reg] += __shfl_xor(pq[reg], mk);
        }
        if ((lane & 15) == 0) {
            eq[hh * 4 + reg][w][0] = pe[reg];
            eq[hh * 4 + reg][w][1] = pq[reg];
        }
    }
    __syncthreads();
    if (tid < 16) {
        float e = 0.f, q = 0.f;
#pragma unroll
        for (int ww = 0; ww < 8; ++ww) { e += eq[tid][ww][0]; q += eq[tid][ww][1]; }
        Ea[row0 + tid] += e + bout[0];
        Qa[row0 + tid] += q + bout[1];
    }
}

// ---------------- k_msg: LDS-staged B + wave-uniform gaussian-window gating ----------------
__global__ __launch_bounds__(512, 2) void k_msg(
    const float* __restrict__ Ra, const float* __restrict__ MI,
    const short* __restrict__ mjTg, const float* __restrict__ centers,
    const float* __restrict__ widths, const float* __restrict__ Wrbf,
    float* __restrict__ MOUT)
{
    __shared__ short Bf[24576];         // 48 KB: hi [0..12287], lo [12288..24575]
    __shared__ float Wt[8192];          // 32 KB
    __shared__ float px[NPER], py[NPER], pz[NPER];

    const int tid  = threadIdx.x;
    const int lane = tid & 63;
    const int w    = tid >> 6;           // 8 waves
    const int mol  = blockIdx.x / (NPER / 8);
    const int ig   = blockIdx.x % (NPER / 8);
    const int base = mol * NPER;
    const int i    = ig * 8 + w;         // this wave's atom

    const int col = lane & 15;
    const int grp = lane >> 4;

    // stage fragment buffer: wave w covers bytes [w*6144, (w+1)*6144)
    {
        const char* src = (const char*)mjTg + (size_t)mol * 49152 + w * 6144 + lane * 16;
        char* dst = (char*)Bf + w * 6144;
#pragma unroll
        for (int it = 0; it < 6; ++it) {
            __builtin_amdgcn_global_load_lds(
                (const __attribute__((address_space(1))) unsigned int*)(src + it * 1024),
                (__attribute__((address_space(3))) unsigned int*)(dst + it * 1024),
                16, 0, 0);
        }
    }
    for (int idx = tid; idx < KR * FD; idx += 512) {
        int k = idx >> 7, f = idx & 127;
        Wt[(k >> 2) * 512 + f * 4 + (k & 3)] = Wrbf[idx];
    }
    if (tid < NPER) {
        px[tid] = Ra[(size_t)(base + tid) * 3 + 0];
        py[tid] = Ra[(size_t)(base + tid) * 3 + 1];
        pz[tid] = Ra[(size_t)(base + tid) * 3 + 2];
    }

    float cent[4], wid[4];
#pragma unroll
    for (int kt = 0; kt < 4; ++kt) {
        cent[kt] = centers[kt * 16 + col];
        wid[kt]  = widths[kt * 16 + col];
    }

    f32x4 acc[4][8];
#pragma unroll
    for (int kt = 0; kt < 4; ++kt)
#pragma unroll
        for (int ft = 0; ft < 8; ++ft)
            acc[kt][ft] = (f32x4){0.f, 0.f, 0.f, 0.f};

    __syncthreads();   // drains vmcnt+lgkm: Bf, Wt, positions all ready

    const float xi = px[i], yi = py[i], zi = pz[i];

    for (int ch = 0; ch < 3; ++ch) {
        // A fragments (rbf) in-register; gaussian-window gating:
        // exp(-w t^2) < e^-20 is below bf16-lo resolution -> skip whole kt
        // group when NO lane is inside the window (wave-uniform branch; x is
        // uniform per j, lanes differ only in center c_k).
        bf16x8 Ahi[4], Alo[4];
#pragma unroll
        for (int e = 0; e < 8; ++e) {
            int jg = ch * 32 + grp * 8 + e;
            float ed = 0.f, cut = 0.f;
            if (jg < NPER) {
                float dx = px[jg] - xi, dy = py[jg] - yi, dz = pz[jg] - zi;
                float d = sqrtf(dx * dx + dy * dy + dz * dz);
                ed = __expf(-d);
                if (jg != i && d < SR_CUT_C) {
                    float xr = d * (1.0f / SR_CUT_C);
                    float xr2 = xr * xr, xr3 = xr2 * xr;
                    cut = 1.0f - xr3 * (6.0f * xr2 - 15.0f * xr + 10.0f);
                }
            }
#pragma unroll
            for (int kt = 0; kt < 4; ++kt) {
                float t = ed - cent[kt];
                float a2 = wid[kt] * t * t;
                if (__any(a2 < 20.0f)) {
                    float val = cut * __expf(-a2);
                    unsigned uv = __float_as_uint(val);
                    Ahi[kt][e] = (short)(uv >> 16);
                    float lv = val - __uint_as_float(uv & 0xFFFF0000u);
                    Alo[kt][e] = (short)(__float_as_uint(lv) >> 16);
                } else {
                    Ahi[kt][e] = 0;
                    Alo[kt][e] = 0;
                }
            }
        }

        const int cb = ch * 4096 + col * 32 + grp * 8;
#pragma unroll
        for (int ft = 0; ft < 8; ++ft) {
            bf16x8 bhi = *(const bf16x8*)&Bf[cb + ft * 512];
            bf16x8 blo = *(const bf16x8*)&Bf[12288 + cb + ft * 512];
            __builtin_amdgcn_s_setprio(1);
#pragma unroll
            for (int kt = 0; kt < 4; ++kt) {
                acc[kt][ft] = __builtin_amdgcn_mfma_f32_16x16x32_bf16(Ahi[kt], bhi, acc[kt][ft], 0, 0, 0);
                acc[kt][ft] = __builtin_amdgcn_mfma_f32_16x16x32_bf16(Alo[kt], bhi, acc[kt][ft], 0, 0, 0);
                acc[kt][ft] = __builtin_amdgcn_mfma_f32_16x16x32_bf16(Ahi[kt], blo, acc[kt][ft], 0, 0, 0);
            }
            __builtin_amdgcn_s_setprio(0);
        }
    }

    // epilogue: part[ft] = sum_k Wrbf[k,f] * T[k,f]
    float part[8];
#pragma unroll
    for (int ft = 0; ft < 8; ++ft) part[ft] = 0.f;
#pragma unroll
    for (int kt = 0; kt < 4; ++kt) {
        const float* wrow = &Wt[(kt * 4 + grp) * 512 + col * 4];
#pragma unroll
        for (int ft = 0; ft < 8; ++ft) {
            float4 w4 = *(const float4*)(wrow + ft * 64);
            part[ft] += acc[kt][ft].x * w4.x + acc[kt][ft].y * w4.y
                      + acc[kt][ft].z * w4.z + acc[kt][ft].w * w4.w;
        }
    }
#pragma unroll
    for (int ft = 0; ft < 8; ++ft) {
        part[ft] += __shfl_xor(part[ft], 16);
        part[ft] += __shfl_xor(part[ft], 32);
    }
    float p0 = (grp == 0) ? part[0] : (grp == 1) ? part[1] : (grp == 2) ? part[2] : part[3];
    float p1 = (grp == 0) ? part[4] : (grp == 1) ? part[5] : (grp == 2) ? part[6] : part[7];
    const size_t go = (size_t)(base + i) * FD;
    MOUT[go + lane]      = MI[go + lane] + p0;
    MOUT[go + 64 + lane] = MI[go + 64 + lane] + p1;
}

// ---------------- finale (unchanged) ----------------
__global__ __launch_bounds__(256) void k_final(
    const int* __restrict__ Za, const float* __restrict__ Ra,
    const float* __restrict__ Escale, const float* __restrict__ Eshift,
    const float* __restrict__ Qscale, const float* __restrict__ Qshift,
    const float* __restrict__ Ea, const float* __restrict__ Qa,
    float* __restrict__ out)
{
    __shared__ float qs[NPER], es[NPER], px[NPER], py[NPER], pz[NPER];
    __shared__ float red[256];
    const int mol = blockIdx.x, t = threadIdx.x;
    float q = 0.f;
    if (t < NPER) {
        int a = mol * NPER + t;
        int z = Za[a];
        es[t] = Escale[z] * Ea[a] + Eshift[z];
        q = Qscale[z] * Qa[a] + Qshift[z];
        px[t] = Ra[(size_t)a * 3 + 0];
        py[t] = Ra[(size_t)a * 3 + 1];
        pz[t] = Ra[(size_t)a * 3 + 2];
    }
    red[t] = q;
    __syncthreads();
    for (int s = 128; s > 0; s >>= 1) {
        if (t < s) red[t] += red[t + s];
        __syncthreads();
    }
    float qavg = red[0] / (float)NPER;
    __syncthreads();
    if (t < NPER) qs[t] = q - qavg;
    red[t] = 0.f;
    __syncthreads();

    float local = 0.f;
    const float c = SR_CUT_C * 0.5f;
    for (int p = t; p < NPER * NPER; p += 256) {
        int i = p / NPER, j = p % NPER;
        if (i == j) continue;
        float dx = px[i] - px[j], dy = py[i] - py[j], dz = pz[i] - pz[j];
        float d2 = dx * dx + dy * dy + dz * dz;
        float d = sqrtf(d2);
        float dS = sqrtf(d2 + 1.0f);
        float sw;
        if (d < c) {
            float xs = d / c;
            float xs2 = xs * xs, xs3 = xs2 * xs;
            sw = xs3 * (6.0f * xs2 - 15.0f * xs + 10.0f);
        } else {
            sw = 1.0f;
        }
        local += KEHALF_C * qs[i] * qs[j] * ((1.0f - sw) / dS + sw / d);
    }
    for (int a = t; a < NPER; a += 256) local += es[a];
    red[t] = local;
    __syncthreads();
    for (int s = 128; s > 0; s >>= 1) {
        if (t < s) red[t] += red[t + s];
        __syncthreads();
    }
    if (t == 0) out[mol] = red[0];
}

extern "C" void kernel_launch(void* const* d_in, const int* in_sizes, int n_in,
                              void* d_out, int out_size, void* d_ws, size_t ws_size,
                              hipStream_t stream)
{
    (void)in_sizes; (void)n_in; (void)out_size; (void)ws_size;

    const int*   Za     = (const int*)d_in[0];
    const float* Ra     = (const float*)d_in[1];
    const float* emb    = (const float*)d_in[5];
    const float* rbfc   = (const float*)d_in[6];
    const float* rbfw   = (const float*)d_in[7];
    const float* Wrbf   = (const float*)d_in[8];
    const float* Wi     = (const float*)d_in[9];
    const float* bi     = (const float*)d_in[10];
    const float* Wj     = (const float*)d_in[11];
    const float* bj     = (const float*)d_in[12];
    const float* rIW    = (const float*)d_in[13];
    const float* rIb    = (const float*)d_in[14];
    const float* Wd     = (const float*)d_in[15];
    const float* bd     = (const float*)d_in[16];
    const float* u      = (const float*)d_in[17];
    const float* rAW    = (const float*)d_in[18];
    const float* rAb    = (const float*)d_in[19];
    const float* rOW    = (const float*)d_in[20];
    const float* rOb    = (const float*)d_in[21];
    const float* Wout   = (const float*)d_in[22];
    const float* bout   = (const float*)d_in[23];
    const float* Escale = (const float*)d_in[24];
    const float* Eshift = (const float*)d_in[25];
    const float* Qscale = (const float*)d_in[26];
    const float* Qshift = (const float*)d_in[27];
    float* outp = (float*)d_out;

    float* ws = (float*)d_ws;
    const size_t NF = (size_t)NATOM * FD;
    float* x  = ws;
    float* mi = ws + NF;
    float* m  = ws + 2 * NF;
    float* Ea = ws + 3 * NF;
    float* Qa = Ea + NATOM;
    short* prepW = (short*)(ws + 3 * NF + 2 * NATOM);
    short* mjTg  = prepW + (size_t)67 * 32768;

    k_prep<<<67, 256, 0, stream>>>(Wi, Wj, rIW, Wd, rAW, rOW, prepW);
    k_first<<<NATOM / 16, 256, 0, stream>>>(Za, emb, prepW, bi, bj, x, mi, mjTg, Ea, Qa);

    for (int b = 0; b < NBLOCK; ++b) {
        k_msg<<<NMOL * (NPER / 8), 512, 0, stream>>>(
            Ra, mi, mjTg, rbfc, rbfw, Wrbf + (size_t)b * KR * FD, m);
        k_tail<<<NATOM / 16, 512, 0, stream>>>(
            m, x, prepW, b, rIb, bd, u, rAb, bi, bj, rOb,
            Wout + (size_t)b * FD * 2, bout + b * 2, mi, mjTg, Ea, Qa);
    }

    k_final<<<NMOL, 256, 0, stream>>>(Za, Ra, Escale, Eshift, Qscale, Qshift, Ea, Qa, outp);
}

// Round 12
// 342.697 us; speedup vs baseline: 1.2501x; 1.0005x over previous
//
#include <hip/hip_runtime.h>

#define NATOM 3840
#define NMOL 48
#define NPER 80
#define FD 128
#define KR 64
#define NBLOCK 5

constexpr float SR_CUT_C = 10.0f;
constexpr float KEHALF_C = 7.199822675975274f;
constexpr float LN2_C    = 0.6931471805599453f;

using bf16x8 = __attribute__((ext_vector_type(8))) short;
using f32x4  = __attribute__((ext_vector_type(4))) float;

__device__ __forceinline__ float sspf(float x) {
    return fmaxf(x, 0.0f) + __logf(1.0f + __expf(-fabsf(x))) - LN2_C;
}

// truncation split: v ~= hi + lo (both bf16), |err| <~ 2^-16 |v|
__device__ __forceinline__ void split2(float v, short& hi, short& lo) {
    unsigned u = __float_as_uint(v);
    hi = (short)(u >> 16);
    float l = v - __uint_as_float(u & 0xFFFF0000u);
    lo = (short)(__float_as_uint(l) >> 16);
}

// ---- mj fragment buffer: per molecule 24576 shorts (hi 0..12287, lo 12288..) ----
// [ch(4096)][f(32)][grp(8)][e]; value (jl, f): ch=jl>>5, grp=(jl>>3)&3, e=jl&7
__device__ __forceinline__ void mj_store(short* mjTg, int gr, int f, float v) {
    int mol = gr / NPER;
    int jl  = gr - mol * NPER;
    short hi, lo; split2(v, hi, lo);
    size_t mo = (size_t)mol * 24576;
    int off = (jl >> 5) * 4096 + f * 32 + ((jl >> 3) & 3) * 8 + (jl & 7);
    mjTg[mo + off] = hi;
    mjTg[mo + 12288 + off] = lo;
}

// activation planes: [16 rows][128 f] shorts, 16B-slot XOR swizzle
__device__ __forceinline__ int plane_idx(int r, int f) {
    int s = f >> 3;
    int sp = (s & 8) | ((s ^ (r & 7)) & 7);
    return r * 128 + sp * 8 + (f & 7);
}

__device__ __forceinline__ void plane_store(short* Ahi, short* Alo, int r, int f, float v) {
    int idx = plane_idx(r, f);
    short hi, lo; split2(v, hi, lo);
    Ahi[idx] = hi; Alo[idx] = lo;
}

// 4-wave variant: wave stages its 16KB quarter (fq = 2w,2w+1)
__device__ __forceinline__ void stage_w_wave(short* dstBase, const short* srcBase, int w, int lane) {
#pragma unroll
    for (int it = 0; it < 16; ++it) {
        int boff = w * 16384 + it * 1024;
        __builtin_amdgcn_global_load_lds(
            (const __attribute__((address_space(1))) unsigned int*)((const char*)srcBase + boff + lane * 16),
            (__attribute__((address_space(3))) unsigned int*)((char*)dstBase + boff),
            16, 0, 0);
    }
}

// 8-wave variant: wave stages its 8KB eighth (fq = w)
__device__ __forceinline__ void stage_w_wave8(short* dstBase, const short* srcBase, int w, int lane) {
#pragma unroll
    for (int it = 0; it < 8; ++it) {
        int boff = w * 8192 + it * 1024;
        __builtin_amdgcn_global_load_lds(
            (const __attribute__((address_space(1))) unsigned int*)((const char*)srcBase + boff + lane * 16),
            (__attribute__((address_space(3))) unsigned int*)((char*)dstBase + boff),
            16, 0, 0);
    }
}

// 2-ft gemm (k_first): C[16 x 32] = planes @ W[:, fq0*16 .. fq0*16+31]
__device__ __forceinline__ void gemm_core(const short* Ahi, const short* Alo,
    const short* Wl, int lane, int fq0, f32x4 acc[2])
{
    const int r = lane & 15, h = lane >> 4;
    bf16x8 afh[4], afl[4];
#pragma unroll
    for (int kt = 0; kt < 4; ++kt) {
        int s = kt * 4 + h;
        int sp = (s & 8) | ((s ^ (r & 7)) & 7);
        afh[kt] = *(const bf16x8*)&Ahi[r * 128 + sp * 8];
        afl[kt] = *(const bf16x8*)&Alo[r * 128 + sp * 8];
    }
#pragma unroll
    for (int ft = 0; ft < 2; ++ft) {
        f32x4 a = {0.f, 0.f, 0.f, 0.f};
#pragma unroll
        for (int kt = 0; kt < 4; ++kt) {
            const short* bp = &Wl[((fq0 + ft) * 4 + kt) * 1024 + lane * 8];
            bf16x8 bh = *(const bf16x8*)bp;
            bf16x8 bl = *(const bf16x8*)(bp + 512);
            a = __builtin_amdgcn_mfma_f32_16x16x32_bf16(afh[kt], bl, a, 0, 0, 0);
            a = __builtin_amdgcn_mfma_f32_16x16x32_bf16(afl[kt], bh, a, 0, 0, 0);
            a = __builtin_amdgcn_mfma_f32_16x16x32_bf16(afh[kt], bh, a, 0, 0, 0);
        }
        acc[ft] = a;
    }
}

// 1-ft gemm (k_tail 8-wave): C[16 x 16] = planes @ W[:, fq*16 .. fq*16+15]
__device__ __forceinline__ void gemm_core1(const short* Ahi, const short* Alo,
    const short* Wl, int lane, int fq, f32x4& acc)
{
    const int r = lane & 15, h = lane >> 4;
    bf16x8 afh[4], afl[4];
#pragma unroll
    for (int kt = 0; kt < 4; ++kt) {
        int s = kt * 4 + h;
        int sp = (s & 8) | ((s ^ (r & 7)) & 7);
        afh[kt] = *(const bf16x8*)&Ahi[r * 128 + sp * 8];
        afl[kt] = *(const bf16x8*)&Alo[r * 128 + sp * 8];
    }
    f32x4 a = {0.f, 0.f, 0.f, 0.f};
#pragma unroll
    for (int kt = 0; kt < 4; ++kt) {
        const short* bp = &Wl[(fq * 4 + kt) * 1024 + lane * 8];
        bf16x8 bh = *(const bf16x8*)bp;
        bf16x8 bl = *(const bf16x8*)(bp + 512);
        a = __builtin_amdgcn_mfma_f32_16x16x32_bf16(afh[kt], bl, a, 0, 0, 0);
        a = __builtin_amdgcn_mfma_f32_16x16x32_bf16(afl[kt], bh, a, 0, 0, 0);
        a = __builtin_amdgcn_mfma_f32_16x16x32_bf16(afh[kt], bh, a, 0, 0, 0);
    }
    acc = a;
}

// ---------------- weight prep (unchanged) ----------------
__global__ __launch_bounds__(256) void k_prep(
    const float* __restrict__ Wi, const float* __restrict__ Wj,
    const float* __restrict__ rIW, const float* __restrict__ Wd,
    const float* __restrict__ rAW, const float* __restrict__ rOW,
    short* __restrict__ prepW)
{
    const int m = blockIdx.x, tid = threadIdx.x;
    const float* src;
    if (m == 65) src = Wi;
    else if (m == 66) src = Wj;
    else {
        int bb = m / 13, slot = m % 13;
        switch (slot) {
            case 0: case 1: case 2: case 3:
                src = rIW + (size_t)((bb * 2 + (slot >> 1)) * 2 + (slot & 1)) * 16384; break;
            case 4: src = Wd + (size_t)bb * 16384; break;
            case 5: case 6: case 7: case 8: {
                int ss = slot - 5;
                src = rAW + (size_t)((bb * 2 + (ss >> 1)) * 2 + (ss & 1)) * 16384; break;
            }
            case 9:  src = Wi + (size_t)((bb + 1 < 5) ? (bb + 1) : 0) * 16384; break;
            case 10: src = Wj + (size_t)((bb + 1 < 5) ? (bb + 1) : 0) * 16384; break;
            default: src = rOW + (size_t)(bb * 2 + (slot - 11)) * 16384; break;
        }
    }
    short* dst = prepW + (size_t)m * 32768;
#pragma unroll
    for (int i = 0; i < 8; ++i) {
        int tr = tid + i * 256;
        int ft = tr >> 8, kt = (tr >> 6) & 3, l = tr & 63;
        int f = ft * 16 + (l & 15);
        int k0 = kt * 32 + (l >> 4) * 8;
        bf16x8 hi8, lo8;
#pragma unroll
        for (int e = 0; e < 8; ++e) {
            float v = src[(size_t)(k0 + e) * FD + f];
            short hh, ll; split2(v, hh, ll);
            hi8[e] = hh; lo8[e] = ll;
        }
        size_t o = (size_t)(ft * 4 + kt) * 1024 + (size_t)l * 8;
        *(bf16x8*)&dst[o] = hi8;
        *(bf16x8*)&dst[o + 512] = lo8;
    }
}

// ---------------- k_first (unchanged) ----------------
__global__ __launch_bounds__(256) void k_first(
    const int* __restrict__ Za, const float* __restrict__ emb,
    const short* __restrict__ Wprep,
    const float* __restrict__ bi, const float* __restrict__ bj,
    float* __restrict__ X, float* __restrict__ MI, short* __restrict__ mjTg,
    float* __restrict__ Ea, float* __restrict__ Qa)
{
    __shared__ short Ahi[2048], Alo[2048];
    __shared__ short Wl[2][32768];
    const int tid = threadIdx.x, lane = tid & 63, w = tid >> 6;
    const int row0 = blockIdx.x * 16;
    const int fq0 = w * 2;
    const int col0 = w * 32 + (lane & 15), col1 = col0 + 16;
    const int hh = lane >> 4;

    stage_w_wave(Wl[0], Wprep + (size_t)65 * 32768, w, lane);   // Wi(0)

    for (int idx = tid; idx < 2048; idx += 256) {
        int rr = idx >> 7, f = idx & 127;
        float v = emb[(size_t)Za[row0 + rr] * FD + f];
        X[(size_t)(row0 + rr) * FD + f] = v;
        plane_store(Ahi, Alo, rr, f, sspf(v));
    }
    if (tid < 16) { Ea[row0 + tid] = 0.f; Qa[row0 + tid] = 0.f; }
    if ((row0 % NPER) == 0) {
        short* mb = mjTg + (size_t)(row0 / NPER) * 24576;
        for (int idx = tid; idx < 2048; idx += 256) {
            int f = idx >> 4, t = idx & 15;
            mb[8192 + f * 32 + 16 + t] = 0;
            mb[12288 + 8192 + f * 32 + 16 + t] = 0;
        }
    }
    __syncthreads();

    stage_w_wave(Wl[1], Wprep + (size_t)66 * 32768, w, lane);   // Wj(0)

    f32x4 acc[2];
    gemm_core(Ahi, Alo, Wl[0], lane, fq0, acc);
    {
        float b0 = bi[col0], b1 = bi[col1];
#pragma unroll
        for (int reg = 0; reg < 4; ++reg) {
            int rw = hh * 4 + reg;
            MI[(size_t)(row0 + rw) * FD + col0] = sspf(acc[0][reg] + b0);
            MI[(size_t)(row0 + rw) * FD + col1] = sspf(acc[1][reg] + b1);
        }
    }
    asm volatile("s_waitcnt vmcnt(0)" ::: "memory");
    gemm_core(Ahi, Alo, Wl[1], lane, fq0, acc);
    {
        float b0 = bj[col0], b1 = bj[col1];
#pragma unroll
        for (int reg = 0; reg < 4; ++reg) {
            int gr = row0 + hh * 4 + reg;
            mj_store(mjTg, gr, col0, sspf(acc[0][reg] + b0));
            mj_store(mjTg, gr, col1, sspf(acc[1][reg] + b1));
        }
    }
}

// ---------------- k_tail: 8 waves, one fq-quarter (16 cols) per wave ----------------
__global__ __launch_bounds__(512) void k_tail(
    const float* __restrict__ M, float* __restrict__ X,
    const short* __restrict__ Wprep, int b,
    const float* __restrict__ rIb, const float* __restrict__ bd,
    const float* __restrict__ u, const float* __restrict__ rAb,
    const float* __restrict__ bi, const float* __restrict__ bj,
    const float* __restrict__ rOb, const float* __restrict__ Wout,
    const float* __restrict__ bout,
    float* __restrict__ MI, short* __restrict__ mjTg,
    float* __restrict__ Ea, float* __restrict__ Qa)
{
    __shared__ short Ahi[2048], Alo[2048];
    __shared__ short Wl[2][32768];
    __shared__ float eq[16][8][2];

    const int tid = threadIdx.x, lane = tid & 63, w = tid >> 6;  // 8 waves
    const int row0 = blockIdx.x * 16;
    const int NG = (b < 4) ? 13 : 11;
    const int fq = w;
    const int col0 = w * 16 + (lane & 15);
    const int hh = lane >> 4;

    auto lgOf = [&](int gg) { return (b < 4 || gg < 9) ? gg : gg + 2; };

    stage_w_wave8(Wl[0], Wprep + (size_t)(b * 13 + lgOf(0)) * 32768, w, lane);

    float vreg[4], xreg[4];
#pragma unroll
    for (int reg = 0; reg < 4; ++reg) {
        int rw = hh * 4 + reg;
        vreg[reg] = M[(size_t)(row0 + rw) * FD + col0];
        xreg[reg] = X[(size_t)(row0 + rw) * FD + col0];
    }
    for (int idx = tid; idx < 2048; idx += 512) {
        int rr = idx >> 7, f = idx & 127;
        plane_store(Ahi, Alo, rr, f, sspf(M[(size_t)(row0 + rr) * FD + f]));
    }
    __syncthreads();

    f32x4 acc;
    for (int g = 0; g < NG; ++g) {
        const int cur = g & 1;
        if (g > 0) {
            asm volatile("s_waitcnt lgkmcnt(0)\n\ts_barrier" ::: "memory");
            asm volatile("s_waitcnt vmcnt(0)" ::: "memory");
        }
        if (g + 1 < NG)
            stage_w_wave8(Wl[cur ^ 1], Wprep + (size_t)(b * 13 + lgOf(g + 1)) * 32768, w, lane);

        // hoist bias/u loads BEFORE gemm so their latency hides under MFMAs
        int lg = lgOf(g);
        const float* bptr;
        switch (lg) {
            case 0:  bptr = rIb + ((size_t)(b * 2 + 0) * 2 + 0) * FD; break;
            case 1:  bptr = rIb + ((size_t)(b * 2 + 0) * 2 + 1) * FD; break;
            case 2:  bptr = rIb + ((size_t)(b * 2 + 1) * 2 + 0) * FD; break;
            case 3:  bptr = rIb + ((size_t)(b * 2 + 1) * 2 + 1) * FD; break;
            case 4:  bptr = bd + (size_t)b * FD; break;
            case 5:  bptr = rAb + ((size_t)(b * 2 + 0) * 2 + 0) * FD; break;
            case 6:  bptr = rAb + ((size_t)(b * 2 + 0) * 2 + 1) * FD; break;
            case 7:  bptr = rAb + ((size_t)(b * 2 + 1) * 2 + 0) * FD; break;
            case 8:  bptr = rAb + ((size_t)(b * 2 + 1) * 2 + 1) * FD; break;
            case 9:  bptr = bi + (size_t)(b + 1) * FD; break;
            case 10: bptr = bj + (size_t)(b + 1) * FD; break;
            case 11: bptr = rOb + (size_t)(b * 2 + 0) * FD; break;
            default: bptr = rOb + (size_t)(b * 2 + 1) * FD; break;
        }
        float bv0 = bptr[col0];
        float uv0 = 0.f;
        if (lg == 4) uv0 = u[(size_t)b * FD + col0];

        gemm_core1(Ahi, Alo, Wl[cur], lane, fq, acc);

        asm volatile("s_waitcnt lgkmcnt(0)\n\ts_barrier" ::: "memory");

        const bool isT = (lg == 0) | (lg == 2) | (lg == 5) | (lg == 7) | (lg == 11);
        const bool isV = (lg == 1) | (lg == 3) | (lg == 6) | (lg == 8) | (lg == 12);
        if (isT) {
#pragma unroll
            for (int reg = 0; reg < 4; ++reg)
                plane_store(Ahi, Alo, hh * 4 + reg, col0, sspf(acc[reg] + bv0));
        } else if (isV) {
#pragma unroll
            for (int reg = 0; reg < 4; ++reg) {
                int rw = hh * 4 + reg;
                float nv0 = acc[reg] + bv0 + vreg[reg];
                vreg[reg] = nv0;
                if (lg != 12) plane_store(Ahi, Alo, rw, col0, sspf(nv0));
                if (lg == 8)  X[(size_t)(row0 + rw) * FD + col0] = nv0;
            }
        } else if (lg == 4) {
#pragma unroll
            for (int reg = 0; reg < 4; ++reg) {
                float nv0 = acc[reg] + bv0 + uv0 * xreg[reg];
                vreg[reg] = nv0;
                plane_store(Ahi, Alo, hh * 4 + reg, col0, sspf(nv0));
            }
        } else if (lg == 9) {
#pragma unroll
            for (int reg = 0; reg < 4; ++reg)
                MI[(size_t)(row0 + hh * 4 + reg) * FD + col0] = sspf(acc[reg] + bv0);
        } else {   // lg == 10: mj for next block -> fragment layout
#pragma unroll
            for (int reg = 0; reg < 4; ++reg)
                mj_store(mjTg, row0 + hh * 4 + reg, col0, sspf(acc[reg] + bv0));
        }
    }
    // output projection: e/q = ssp(o) @ Wout + bout
    float pe[4], pq[4];
#pragma unroll
    for (int reg = 0; reg < 4; ++reg) {
        float s0 = sspf(vreg[reg]);
        pe[reg] = s0 * Wout[col0 * 2 + 0];
        pq[reg] = s0 * Wout[col0 * 2 + 1];
#pragma unroll
        for (int mk = 1; mk < 16; mk <<= 1) {
            pe[reg] += __shfl_xor(pe[reg], mk);
            pq[reg] += __shfl_xor(pq[reg], mk);
        }
        if ((lane & 15) == 0) {
            eq[hh * 4 + reg][w][0] = pe[reg];
            eq[hh * 4 + reg][w][1] = pq[reg];
        }
    }
    __syncthreads();
    if (tid < 16) {
        float e = 0.f, q = 0.f;
#pragma unroll
        for (int ww = 0; ww < 8; ++ww) { e += eq[tid][ww][0]; q += eq[tid][ww][1]; }
        Ea[row0 + tid] += e + bout[0];
        Qa[row0 + tid] += q + bout[1];
    }
}

// ---------------- k_msg: LDS-staged B + wave-uniform gaussian-window gating ----------------
__global__ __launch_bounds__(512, 2) void k_msg(
    const float* __restrict__ Ra, const float* __restrict__ MI,
    const short* __restrict__ mjTg, const float* __restrict__ centers,
    const float* __restrict__ widths, const float* __restrict__ Wrbf,
    float* __restrict__ MOUT)
{
    __shared__ short Bf[24576];         // 48 KB: hi [0..12287], lo [12288..24575]
    __shared__ float Wt[8192];          // 32 KB
    __shared__ float px[NPER], py[NPER], pz[NPER];

    const int tid  = threadIdx.x;
    const int lane = tid & 63;
    const int w    = tid >> 6;           // 8 waves
    const int mol  = blockIdx.x / (NPER / 8);
    const int ig   = blockIdx.x % (NPER / 8);
    const int base = mol * NPER;
    const int i    = ig * 8 + w;         // this wave's atom

    const int col = lane & 15;
    const int grp = lane >> 4;

    // stage fragment buffer: wave w covers bytes [w*6144, (w+1)*6144)
    {
        const char* src = (const char*)mjTg + (size_t)mol * 49152 + w * 6144 + lane * 16;
        char* dst = (char*)Bf + w * 6144;
#pragma unroll
        for (int it = 0; it < 6; ++it) {
            __builtin_amdgcn_global_load_lds(
                (const __attribute__((address_space(1))) unsigned int*)(src + it * 1024),
                (__attribute__((address_space(3))) unsigned int*)(dst + it * 1024),
                16, 0, 0);
        }
    }
    for (int idx = tid; idx < KR * FD; idx += 512) {
        int k = idx >> 7, f = idx & 127;
        Wt[(k >> 2) * 512 + f * 4 + (k & 3)] = Wrbf[idx];
    }
    if (tid < NPER) {
        px[tid] = Ra[(size_t)(base + tid) * 3 + 0];
        py[tid] = Ra[(size_t)(base + tid) * 3 + 1];
        pz[tid] = Ra[(size_t)(base + tid) * 3 + 2];
    }

    float cent[4], wid[4];
#pragma unroll
    for (int kt = 0; kt < 4; ++kt) {
        cent[kt] = centers[kt * 16 + col];
        wid[kt]  = widths[kt * 16 + col];
    }

    f32x4 acc[4][8];
#pragma unroll
    for (int kt = 0; kt < 4; ++kt)
#pragma unroll
        for (int ft = 0; ft < 8; ++ft)
            acc[kt][ft] = (f32x4){0.f, 0.f, 0.f, 0.f};

    __syncthreads();   // drains vmcnt+lgkm: Bf, Wt, positions all ready

    const float xi = px[i], yi = py[i], zi = pz[i];

    for (int ch = 0; ch < 3; ++ch) {
        // A fragments (rbf) in-register; gaussian-window gating:
        // exp(-w t^2) < e^-20 is below bf16-lo resolution -> skip whole kt
        // group when NO lane is inside the window (wave-uniform branch; x is
        // uniform per j, lanes differ only in center c_k).
        bf16x8 Ahi[4], Alo[4];
#pragma unroll
        for (int e = 0; e < 8; ++e) {
            int jg = ch * 32 + grp * 8 + e;
            float ed = 0.f, cut = 0.f;
            if (jg < NPER) {
                float dx = px[jg] - xi, dy = py[jg] - yi, dz = pz[jg] - zi;
                float d = sqrtf(dx * dx + dy * dy + dz * dz);
                ed = __expf(-d);
                if (jg != i && d < SR_CUT_C) {
                    float xr = d * (1.0f / SR_CUT_C);
                    float xr2 = xr * xr, xr3 = xr2 * xr;
                    cut = 1.0f - xr3 * (6.0f * xr2 - 15.0f * xr + 10.0f);
                }
            }
#pragma unroll
            for (int kt = 0; kt < 4; ++kt) {
                float t = ed - cent[kt];
                float a2 = wid[kt] * t * t;
                if (__any(a2 < 20.0f)) {
                    float val = cut * __expf(-a2);
                    unsigned uv = __float_as_uint(val);
                    Ahi[kt][e] = (short)(uv >> 16);
                    float lv = val - __uint_as_float(uv & 0xFFFF0000u);
                    Alo[kt][e] = (short)(__float_as_uint(lv) >> 16);
                } else {
                    Ahi[kt][e] = 0;
                    Alo[kt][e] = 0;
                }
            }
        }

        const int cb = ch * 4096 + col * 32 + grp * 8;
#pragma unroll
        for (int ft = 0; ft < 8; ++ft) {
            bf16x8 bhi = *(const bf16x8*)&Bf[cb + ft * 512];
            bf16x8 blo = *(const bf16x8*)&Bf[12288 + cb + ft * 512];
            __builtin_amdgcn_s_setprio(1);
#pragma unroll
            for (int kt = 0; kt < 4; ++kt) {
                acc[kt][ft] = __builtin_amdgcn_mfma_f32_16x16x32_bf16(Ahi[kt], bhi, acc[kt][ft], 0, 0, 0);
                acc[kt][ft] = __builtin_amdgcn_mfma_f32_16x16x32_bf16(Alo[kt], bhi, acc[kt][ft], 0, 0, 0);
                acc[kt][ft] = __builtin_amdgcn_mfma_f32_16x16x32_bf16(Ahi[kt], blo, acc[kt][ft], 0, 0, 0);
            }
            __builtin_amdgcn_s_setprio(0);
        }
    }

    // epilogue: part[ft] = sum_k Wrbf[k,f] * T[k,f]
    float part[8];
#pragma unroll
    for (int ft = 0; ft < 8; ++ft) part[ft] = 0.f;
#pragma unroll
    for (int kt = 0; kt < 4; ++kt) {
        const float* wrow = &Wt[(kt * 4 + grp) * 512 + col * 4];
#pragma unroll
        for (int ft = 0; ft < 8; ++ft) {
            float4 w4 = *(const float4*)(wrow + ft * 64);
            part[ft] += acc[kt][ft].x * w4.x + acc[kt][ft].y * w4.y
                      + acc[kt][ft].z * w4.z + acc[kt][ft].w * w4.w;
        }
    }
#pragma unroll
    for (int ft = 0; ft < 8; ++ft) {
        part[ft] += __shfl_xor(part[ft], 16);
        part[ft] += __shfl_xor(part[ft], 32);
    }
    float p0 = (grp == 0) ? part[0] : (grp == 1) ? part[1] : (grp == 2) ? part[2] : part[3];
    float p1 = (grp == 0) ? part[4] : (grp == 1) ? part[5] : (grp == 2) ? part[6] : part[7];
    const size_t go = (size_t)(base + i) * FD;
    MOUT[go + lane]      = MI[go + lane] + p0;
    MOUT[go + 64 + lane] = MI[go + 64 + lane] + p1;
}

// ---------------- finale (unchanged) ----------------
__global__ __launch_bounds__(256) void k_final(
    const int* __restrict__ Za, const float* __restrict__ Ra,
    const float* __restrict__ Escale, const float* __restrict__ Eshift,
    const float* __restrict__ Qscale, const float* __restrict__ Qshift,
    const float* __restrict__ Ea, const float* __restrict__ Qa,
    float* __restrict__ out)
{
    __shared__ float qs[NPER], es[NPER], px[NPER], py[NPER], pz[NPER];
    __shared__ float red[256];
    const int mol = blockIdx.x, t = threadIdx.x;
    float q = 0.f;
    if (t < NPER) {
        int a = mol * NPER + t;
        int z = Za[a];
        es[t] = Escale[z] * Ea[a] + Eshift[z];
        q = Qscale[z] * Qa[a] + Qshift[z];
        px[t] = Ra[(size_t)a * 3 + 0];
        py[t] = Ra[(size_t)a * 3 + 1];
        pz[t] = Ra[(size_t)a * 3 + 2];
    }
    red[t] = q;
    __syncthreads();
    for (int s = 128; s > 0; s >>= 1) {
        if (t < s) red[t] += red[t + s];
        __syncthreads();
    }
    float qavg = red[0] / (float)NPER;
    __syncthreads();
    if (t < NPER) qs[t] = q - qavg;
    red[t] = 0.f;
    __syncthreads();

    float local = 0.f;
    const float c = SR_CUT_C * 0.5f;
    for (int p = t; p < NPER * NPER; p += 256) {
        int i = p / NPER, j = p % NPER;
        if (i == j) continue;
        float dx = px[i] - px[j], dy = py[i] - py[j], dz = pz[i] - pz[j];
        float d2 = dx * dx + dy * dy + dz * dz;
        float d = sqrtf(d2);
        float dS = sqrtf(d2 + 1.0f);
        float sw;
        if (d < c) {
            float xs = d / c;
            float xs2 = xs * xs, xs3 = xs2 * xs;
            sw = xs3 * (6.0f * xs2 - 15.0f * xs + 10.0f);
        } else {
            sw = 1.0f;
        }
        local += KEHALF_C * qs[i] * qs[j] * ((1.0f - sw) / dS + sw / d);
    }
    for (int a = t; a < NPER; a += 256) local += es[a];
    red[t] = local;
    __syncthreads();
    for (int s = 128; s > 0; s >>= 1) {
        if (t < s) red[t] += red[t + s];
        __syncthreads();
    }
    if (t == 0) out[mol] = red[0];
}

extern "C" void kernel_launch(void* const* d_in, const int* in_sizes, int n_in,
                              void* d_out, int out_size, void* d_ws, size_t ws_size,
                              hipStream_t stream)
{
    (void)in_sizes; (void)n_in; (void)out_size; (void)ws_size;

    const int*   Za     = (const int*)d_in[0];
    const float* Ra     = (const float*)d_in[1];
    const float* emb    = (const float*)d_in[5];
    const float* rbfc   = (const float*)d_in[6];
    const float* rbfw   = (const float*)d_in[7];
    const float* Wrbf   = (const float*)d_in[8];
    const float* Wi     = (const float*)d_in[9];
    const float* bi     = (const float*)d_in[10];
    const float* Wj     = (const float*)d_in[11];
    const float* bj     = (const float*)d_in[12];
    const float* rIW    = (const float*)d_in[13];
    const float* rIb    = (const float*)d_in[14];
    const float* Wd     = (const float*)d_in[15];
    const float* bd     = (const float*)d_in[16];
    const float* u      = (const float*)d_in[17];
    const float* rAW    = (const float*)d_in[18];
    const float* rAb    = (const float*)d_in[19];
    const float* rOW    = (const float*)d_in[20];
    const float* rOb    = (const float*)d_in[21];
    const float* Wout   = (const float*)d_in[22];
    const float* bout   = (const float*)d_in[23];
    const float* Escale = (const float*)d_in[24];
    const float* Eshift = (const float*)d_in[25];
    const float* Qscale = (const float*)d_in[26];
    const float* Qshift = (const float*)d_in[27];
    float* outp = (float*)d_out;

    float* ws = (float*)d_ws;
    const size_t NF = (size_t)NATOM * FD;
    float* x  = ws;
    float* mi = ws + NF;
    float* m  = ws + 2 * NF;
    float* Ea = ws + 3 * NF;
    float* Qa = Ea + NATOM;
    short* prepW = (short*)(ws + 3 * NF + 2 * NATOM);
    short* mjTg  = prepW + (size_t)67 * 32768;

    k_prep<<<67, 256, 0, stream>>>(Wi, Wj, rIW, Wd, rAW, rOW, prepW);
    k_first<<<NATOM / 16, 256, 0, stream>>>(Za, emb, prepW, bi, bj, x, mi, mjTg, Ea, Qa);

    for (int b = 0; b < NBLOCK; ++b) {
        k_msg<<<NMOL * (NPER / 8), 512, 0, stream>>>(
            Ra, mi, mjTg, rbfc, rbfw, Wrbf + (size_t)b * KR * FD, m);
        k_tail<<<NATOM / 16, 512, 0, stream>>>(
            m, x, prepW, b, rIb, bd, u, rAb, bi, bj, rOb,
            Wout + (size_t)b * FD * 2, bout + b * 2, mi, mjTg, Ea, Qa);
    }

    k_final<<<NMOL, 256, 0, stream>>>(Za, Ra, Escale, Eshift, Qscale, Qshift, Ea, Qa, outp);
}

// Round 13
// 302.773 us; speedup vs baseline: 1.4150x; 1.1319x over previous
//
#include <hip/hip_runtime.h>

#define NATOM 3840
#define NMOL 48
#define NPER 80
#define FD 128
#define KR 64
#define NBLOCK 5

constexpr float SR_CUT_C = 10.0f;
constexpr float KEHALF_C = 7.199822675975274f;
constexpr float LN2_C    = 0.6931471805599453f;

using bf16x8 = __attribute__((ext_vector_type(8))) short;
using f32x4  = __attribute__((ext_vector_type(4))) float;

__device__ __forceinline__ float sspf(float x) {
    return fmaxf(x, 0.0f) + __logf(1.0f + __expf(-fabsf(x))) - LN2_C;
}

__device__ __forceinline__ void split2(float v, short& hi, short& lo) {
    unsigned u = __float_as_uint(v);
    hi = (short)(u >> 16);
    float l = v - __uint_as_float(u & 0xFFFF0000u);
    lo = (short)(__float_as_uint(l) >> 16);
}

// ---- mj fragment buffer: per molecule 24576 shorts (hi 0..12287, lo 12288..) ----
// [ch(4096)][f(32)][grp(8)][e]; value (jl, f): ch=jl>>5, grp=(jl>>3)&3, e=jl&7
__device__ __forceinline__ void mj_store(short* mjTg, int gr, int f, float v) {
    int mol = gr / NPER;
    int jl  = gr - mol * NPER;
    short hi, lo; split2(v, hi, lo);
    size_t mo = (size_t)mol * 24576;
    int off = (jl >> 5) * 4096 + f * 32 + ((jl >> 3) & 3) * 8 + (jl & 7);
    mjTg[mo + off] = hi;
    mjTg[mo + 12288 + off] = lo;
}

// activation planes: [16 rows][128 f] shorts, 16B-slot XOR swizzle
__device__ __forceinline__ int plane_idx(int r, int f) {
    int s = f >> 3;
    int sp = (s & 8) | ((s ^ (r & 7)) & 7);
    return r * 128 + sp * 8 + (f & 7);
}

__device__ __forceinline__ void plane_store(short* Ahi, short* Alo, int r, int f, float v) {
    int idx = plane_idx(r, f);
    short hi, lo; split2(v, hi, lo);
    Ahi[idx] = hi; Alo[idx] = lo;
}

// 4-wave variant (k_first): wave stages its 16KB quarter (fq = 2w,2w+1)
__device__ __forceinline__ void stage_w_wave(short* dstBase, const short* srcBase, int w, int lane) {
#pragma unroll
    for (int it = 0; it < 16; ++it) {
        int boff = w * 16384 + it * 1024;
        __builtin_amdgcn_global_load_lds(
            (const __attribute__((address_space(1))) unsigned int*)((const char*)srcBase + boff + lane * 16),
            (__attribute__((address_space(3))) unsigned int*)((char*)dstBase + boff),
            16, 0, 0);
    }
}

// 8-wave variant: wave stages its 8KB eighth (fq = w)
__device__ __forceinline__ void stage_w_wave8(short* dstBase, const short* srcBase, int w, int lane) {
#pragma unroll
    for (int it = 0; it < 8; ++it) {
        int boff = w * 8192 + it * 1024;
        __builtin_amdgcn_global_load_lds(
            (const __attribute__((address_space(1))) unsigned int*)((const char*)srcBase + boff + lane * 16),
            (__attribute__((address_space(3))) unsigned int*)((char*)dstBase + boff),
            16, 0, 0);
    }
}

// 2-ft gemm (k_first): C[16 x 32] = planes @ W[:, fq0*16 .. fq0*16+31]
__device__ __forceinline__ void gemm_core(const short* Ahi, const short* Alo,
    const short* Wl, int lane, int fq0, f32x4 acc[2])
{
    const int r = lane & 15, h = lane >> 4;
    bf16x8 afh[4], afl[4];
#pragma unroll
    for (int kt = 0; kt < 4; ++kt) {
        int s = kt * 4 + h;
        int sp = (s & 8) | ((s ^ (r & 7)) & 7);
        afh[kt] = *(const bf16x8*)&Ahi[r * 128 + sp * 8];
        afl[kt] = *(const bf16x8*)&Alo[r * 128 + sp * 8];
    }
#pragma unroll
    for (int ft = 0; ft < 2; ++ft) {
        f32x4 a = {0.f, 0.f, 0.f, 0.f};
#pragma unroll
        for (int kt = 0; kt < 4; ++kt) {
            const short* bp = &Wl[((fq0 + ft) * 4 + kt) * 1024 + lane * 8];
            bf16x8 bh = *(const bf16x8*)bp;
            bf16x8 bl = *(const bf16x8*)(bp + 512);
            a = __builtin_amdgcn_mfma_f32_16x16x32_bf16(afh[kt], bl, a, 0, 0, 0);
            a = __builtin_amdgcn_mfma_f32_16x16x32_bf16(afl[kt], bh, a, 0, 0, 0);
            a = __builtin_amdgcn_mfma_f32_16x16x32_bf16(afh[kt], bh, a, 0, 0, 0);
        }
        acc[ft] = a;
    }
}

// 1-ft gemm (8-wave): C[16 x 16] = planes @ W[:, fq*16 .. fq*16+15]
__device__ __forceinline__ void gemm_core1(const short* Ahi, const short* Alo,
    const short* Wl, int lane, int fq, f32x4& acc)
{
    const int r = lane & 15, h = lane >> 4;
    bf16x8 afh[4], afl[4];
#pragma unroll
    for (int kt = 0; kt < 4; ++kt) {
        int s = kt * 4 + h;
        int sp = (s & 8) | ((s ^ (r & 7)) & 7);
        afh[kt] = *(const bf16x8*)&Ahi[r * 128 + sp * 8];
        afl[kt] = *(const bf16x8*)&Alo[r * 128 + sp * 8];
    }
    f32x4 a = {0.f, 0.f, 0.f, 0.f};
#pragma unroll
    for (int kt = 0; kt < 4; ++kt) {
        const short* bp = &Wl[(fq * 4 + kt) * 1024 + lane * 8];
        bf16x8 bh = *(const bf16x8*)bp;
        bf16x8 bl = *(const bf16x8*)(bp + 512);
        a = __builtin_amdgcn_mfma_f32_16x16x32_bf16(afh[kt], bl, a, 0, 0, 0);
        a = __builtin_amdgcn_mfma_f32_16x16x32_bf16(afl[kt], bh, a, 0, 0, 0);
        a = __builtin_amdgcn_mfma_f32_16x16x32_bf16(afh[kt], bh, a, 0, 0, 0);
    }
    acc = a;
}

// ---------------- weight prep (unchanged) ----------------
__global__ __launch_bounds__(256) void k_prep(
    const float* __restrict__ Wi, const float* __restrict__ Wj,
    const float* __restrict__ rIW, const float* __restrict__ Wd,
    const float* __restrict__ rAW, const float* __restrict__ rOW,
    short* __restrict__ prepW)
{
    const int m = blockIdx.x, tid = threadIdx.x;
    const float* src;
    if (m == 65) src = Wi;
    else if (m == 66) src = Wj;
    else {
        int bb = m / 13, slot = m % 13;
        switch (slot) {
            case 0: case 1: case 2: case 3:
                src = rIW + (size_t)((bb * 2 + (slot >> 1)) * 2 + (slot & 1)) * 16384; break;
            case 4: src = Wd + (size_t)bb * 16384; break;
            case 5: case 6: case 7: case 8: {
                int ss = slot - 5;
                src = rAW + (size_t)((bb * 2 + (ss >> 1)) * 2 + (ss & 1)) * 16384; break;
            }
            case 9:  src = Wi + (size_t)((bb + 1 < 5) ? (bb + 1) : 0) * 16384; break;
            case 10: src = Wj + (size_t)((bb + 1 < 5) ? (bb + 1) : 0) * 16384; break;
            default: src = rOW + (size_t)(bb * 2 + (slot - 11)) * 16384; break;
        }
    }
    short* dst = prepW + (size_t)m * 32768;
#pragma unroll
    for (int i = 0; i < 8; ++i) {
        int tr = tid + i * 256;
        int ft = tr >> 8, kt = (tr >> 6) & 3, l = tr & 63;
        int f = ft * 16 + (l & 15);
        int k0 = kt * 32 + (l >> 4) * 8;
        bf16x8 hi8, lo8;
#pragma unroll
        for (int e = 0; e < 8; ++e) {
            float v = src[(size_t)(k0 + e) * FD + f];
            short hh, ll; split2(v, hh, ll);
            hi8[e] = hh; lo8[e] = ll;
        }
        size_t o = (size_t)(ft * 4 + kt) * 1024 + (size_t)l * 8;
        *(bf16x8*)&dst[o] = hi8;
        *(bf16x8*)&dst[o + 512] = lo8;
    }
}

// ---------------- k_first (unchanged) ----------------
__global__ __launch_bounds__(256) void k_first(
    const int* __restrict__ Za, const float* __restrict__ emb,
    const short* __restrict__ Wprep,
    const float* __restrict__ bi, const float* __restrict__ bj,
    float* __restrict__ X, float* __restrict__ MI, short* __restrict__ mjTg,
    float* __restrict__ Ea, float* __restrict__ Qa)
{
    __shared__ short Ahi[2048], Alo[2048];
    __shared__ short Wl[2][32768];
    const int tid = threadIdx.x, lane = tid & 63, w = tid >> 6;
    const int row0 = blockIdx.x * 16;
    const int fq0 = w * 2;
    const int col0 = w * 32 + (lane & 15), col1 = col0 + 16;
    const int hh = lane >> 4;

    stage_w_wave(Wl[0], Wprep + (size_t)65 * 32768, w, lane);   // Wi(0)

    for (int idx = tid; idx < 2048; idx += 256) {
        int rr = idx >> 7, f = idx & 127;
        float v = emb[(size_t)Za[row0 + rr] * FD + f];
        X[(size_t)(row0 + rr) * FD + f] = v;
        plane_store(Ahi, Alo, rr, f, sspf(v));
    }
    if (tid < 16) { Ea[row0 + tid] = 0.f; Qa[row0 + tid] = 0.f; }
    if ((row0 % NPER) == 0) {
        short* mb = mjTg + (size_t)(row0 / NPER) * 24576;
        for (int idx = tid; idx < 2048; idx += 256) {
            int f = idx >> 4, t = idx & 15;
            mb[8192 + f * 32 + 16 + t] = 0;
            mb[12288 + 8192 + f * 32 + 16 + t] = 0;
        }
    }
    __syncthreads();

    stage_w_wave(Wl[1], Wprep + (size_t)66 * 32768, w, lane);   // Wj(0)

    f32x4 acc[2];
    gemm_core(Ahi, Alo, Wl[0], lane, fq0, acc);
    {
        float b0 = bi[col0], b1 = bi[col1];
#pragma unroll
        for (int reg = 0; reg < 4; ++reg) {
            int rw = hh * 4 + reg;
            MI[(size_t)(row0 + rw) * FD + col0] = sspf(acc[0][reg] + b0);
            MI[(size_t)(row0 + rw) * FD + col1] = sspf(acc[1][reg] + b1);
        }
    }
    asm volatile("s_waitcnt vmcnt(0)" ::: "memory");
    gemm_core(Ahi, Alo, Wl[1], lane, fq0, acc);
    {
        float b0 = bj[col0], b1 = bj[col1];
#pragma unroll
        for (int reg = 0; reg < 4; ++reg) {
            int gr = row0 + hh * 4 + reg;
            mj_store(mjTg, gr, col0, sspf(acc[0][reg] + b0));
            mj_store(mjTg, gr, col1, sspf(acc[1][reg] + b1));
        }
    }
}

// ---------------- k_fused: Phase M (message) + Phase T (13-GEMM chain) ----------------
// Block owns 16 atom rows. LDS overlay:
//   Phase M: Bf = uni[0,48K), Wt = uni[96K,128K)
//   Phase T: Wl0 = uni[0,64K), Wl1 = uni[64K,128K)
// Separation: single __syncthreads after Phase M (Bf/Wt dead, mst complete).
__global__ __launch_bounds__(512, 2) void k_fused(
    const float* __restrict__ Ra, float* __restrict__ X,
    const short* __restrict__ Wprep, int b,
    const float* __restrict__ centers, const float* __restrict__ widths,
    const float* __restrict__ Wrbf,
    const float* __restrict__ rIb, const float* __restrict__ bd,
    const float* __restrict__ u, const float* __restrict__ rAb,
    const float* __restrict__ bi, const float* __restrict__ bj,
    const float* __restrict__ rOb, const float* __restrict__ Wout,
    const float* __restrict__ bout,
    float* __restrict__ MI, short* __restrict__ mjTg,
    float* __restrict__ Ea, float* __restrict__ Qa)
{
    __shared__ short Ahi[2048], Alo[2048];   // activation planes (8 KB)
    __shared__ char  uni[131072];            // 128 KB overlay
    __shared__ float mst[16][128];           // m staging, fp32 (8 KB)
    __shared__ float px[NPER], py[NPER], pz[NPER];
    __shared__ float eq[16][8][2];

    short* Bf  = (short*)uni;
    float* Wt  = (float*)(uni + 98304);
    short* Wl0 = (short*)uni;
    short* Wl1 = (short*)(uni + 65536);

    const int tid = threadIdx.x, lane = tid & 63, w = tid >> 6;   // 8 waves
    const int row0 = blockIdx.x * 16;
    const int mol  = row0 / NPER;
    const int iloc0 = row0 - mol * NPER;     // molecule-local base of our 16 atoms
    const int NG = (b < 4) ? 13 : 11;
    const int col = lane & 15;
    const int grp = lane >> 4;
    const int hh  = lane >> 4;
    const int col0 = w * 16 + (lane & 15);   // phase-T column

    auto lgOf = [&](int gg) { return (b < 4 || gg < 9) ? gg : gg + 2; };

    // ---- stage: Bf (48 KB molecule fragments), Wt (Wrbf), positions, X/MI regs ----
    {
        const char* src = (const char*)mjTg + (size_t)mol * 49152 + w * 6144 + lane * 16;
        char* dst = (char*)Bf + w * 6144;
#pragma unroll
        for (int it = 0; it < 6; ++it) {
            __builtin_amdgcn_global_load_lds(
                (const __attribute__((address_space(1))) unsigned int*)(src + it * 1024),
                (__attribute__((address_space(3))) unsigned int*)(dst + it * 1024),
                16, 0, 0);
        }
    }
    for (int idx = tid; idx < KR * FD; idx += 512) {
        int k = idx >> 7, f = idx & 127;
        Wt[(k >> 2) * 512 + f * 4 + (k & 3)] = Wrbf[idx];
    }
    if (tid < NPER) {
        px[tid] = Ra[(size_t)(mol * NPER + tid) * 3 + 0];
        py[tid] = Ra[(size_t)(mol * NPER + tid) * 3 + 1];
        pz[tid] = Ra[(size_t)(mol * NPER + tid) * 3 + 2];
    }
    float xreg[4];
#pragma unroll
    for (int reg = 0; reg < 4; ++reg)
        xreg[reg] = X[(size_t)(row0 + hh * 4 + reg) * FD + col0];
    // MI values for this wave's 2 atoms (rows 2w, 2w+1) at f = lane, 64+lane
    float mi0l = MI[(size_t)(row0 + 2 * w) * FD + lane];
    float mi0h = MI[(size_t)(row0 + 2 * w) * FD + 64 + lane];
    float mi1l = MI[(size_t)(row0 + 2 * w + 1) * FD + lane];
    float mi1h = MI[(size_t)(row0 + 2 * w + 1) * FD + 64 + lane];

    float cent[4], wid[4];
#pragma unroll
    for (int kt = 0; kt < 4; ++kt) {
        cent[kt] = centers[kt * 16 + col];
        wid[kt]  = widths[kt * 16 + col];
    }

    __syncthreads();   // full drain: Bf, Wt, positions ready

    // ---------------- Phase M: 2 atoms per wave ----------------
#pragma unroll
    for (int a2 = 0; a2 < 2; ++a2) {
        const int rl = 2 * w + a2;
        const int i  = iloc0 + rl;
        const float xi = px[i], yi = py[i], zi = pz[i];

        f32x4 acc[4][8];
#pragma unroll
        for (int kt = 0; kt < 4; ++kt)
#pragma unroll
            for (int ft = 0; ft < 8; ++ft)
                acc[kt][ft] = (f32x4){0.f, 0.f, 0.f, 0.f};

        for (int ch = 0; ch < 3; ++ch) {
            bf16x8 Fhi[4], Flo[4];
#pragma unroll
            for (int e = 0; e < 8; ++e) {
                int jg = ch * 32 + grp * 8 + e;
                float ed = 0.f, cut = 0.f;
                if (jg < NPER) {
                    float dx = px[jg] - xi, dy = py[jg] - yi, dz = pz[jg] - zi;
                    float d = sqrtf(dx * dx + dy * dy + dz * dz);
                    ed = __expf(-d);
                    if (jg != i && d < SR_CUT_C) {
                        float xr = d * (1.0f / SR_CUT_C);
                        float xr2 = xr * xr, xr3 = xr2 * xr;
                        cut = 1.0f - xr3 * (6.0f * xr2 - 15.0f * xr + 10.0f);
                    }
                }
#pragma unroll
                for (int kt = 0; kt < 4; ++kt) {
                    float t = ed - cent[kt];
                    float a2v = wid[kt] * t * t;
                    if (__any(a2v < 20.0f)) {
                        float val = cut * __expf(-a2v);
                        unsigned uv = __float_as_uint(val);
                        Fhi[kt][e] = (short)(uv >> 16);
                        float lv = val - __uint_as_float(uv & 0xFFFF0000u);
                        Flo[kt][e] = (short)(__float_as_uint(lv) >> 16);
                    } else {
                        Fhi[kt][e] = 0;
                        Flo[kt][e] = 0;
                    }
                }
            }
            const int cb = ch * 4096 + col * 32 + grp * 8;
#pragma unroll
            for (int ft = 0; ft < 8; ++ft) {
                bf16x8 bhi = *(const bf16x8*)&Bf[cb + ft * 512];
                bf16x8 blo = *(const bf16x8*)&Bf[12288 + cb + ft * 512];
                __builtin_amdgcn_s_setprio(1);
#pragma unroll
                for (int kt = 0; kt < 4; ++kt) {
                    acc[kt][ft] = __builtin_amdgcn_mfma_f32_16x16x32_bf16(Fhi[kt], bhi, acc[kt][ft], 0, 0, 0);
                    acc[kt][ft] = __builtin_amdgcn_mfma_f32_16x16x32_bf16(Flo[kt], bhi, acc[kt][ft], 0, 0, 0);
                    acc[kt][ft] = __builtin_amdgcn_mfma_f32_16x16x32_bf16(Fhi[kt], blo, acc[kt][ft], 0, 0, 0);
                }
                __builtin_amdgcn_s_setprio(0);
            }
        }

        // contract with Wrbf; reduce over k
        float part[8];
#pragma unroll
        for (int ft = 0; ft < 8; ++ft) part[ft] = 0.f;
#pragma unroll
        for (int kt = 0; kt < 4; ++kt) {
            const float* wrow = &Wt[(kt * 4 + grp) * 512 + col * 4];
#pragma unroll
            for (int ft = 0; ft < 8; ++ft) {
                float4 w4 = *(const float4*)(wrow + ft * 64);
                part[ft] += acc[kt][ft].x * w4.x + acc[kt][ft].y * w4.y
                          + acc[kt][ft].z * w4.z + acc[kt][ft].w * w4.w;
            }
        }
#pragma unroll
        for (int ft = 0; ft < 8; ++ft) {
            part[ft] += __shfl_xor(part[ft], 16);
            part[ft] += __shfl_xor(part[ft], 32);
        }
        float p0 = (grp == 0) ? part[0] : (grp == 1) ? part[1] : (grp == 2) ? part[2] : part[3];
        float p1 = (grp == 0) ? part[4] : (grp == 1) ? part[5] : (grp == 2) ? part[6] : part[7];
        float m0 = (a2 ? mi1l : mi0l) + p0;
        float m1 = (a2 ? mi1h : mi0h) + p1;
        mst[rl][lane]      = m0;
        mst[rl][64 + lane] = m1;
        plane_store(Ahi, Alo, rl, lane,      sspf(m0));
        plane_store(Ahi, Alo, rl, 64 + lane, sspf(m1));
    }

    __syncthreads();   // Phase M complete: Bf/Wt dead, mst + planes ready

    // issue first W stage into region A (overlaps dead Bf)
    stage_w_wave8(Wl0, Wprep + (size_t)(b * 13 + lgOf(0)) * 32768, w, lane);

    float vreg[4];
#pragma unroll
    for (int reg = 0; reg < 4; ++reg)
        vreg[reg] = mst[hh * 4 + reg][col0];

    // ---------------- Phase T: 13-GEMM chain ----------------
    f32x4 acc1;
    for (int g = 0; g < NG; ++g) {
        const int cur = g & 1;
        short* Wcur = cur ? Wl1 : Wl0;
        short* Wnxt = cur ? Wl0 : Wl1;
        if (g > 0)
            asm volatile("s_waitcnt lgkmcnt(0)\n\ts_barrier" ::: "memory");
        asm volatile("s_waitcnt vmcnt(0)" ::: "memory");   // my W eighth staged
        if (g + 1 < NG)
            stage_w_wave8(Wnxt, Wprep + (size_t)(b * 13 + lgOf(g + 1)) * 32768, w, lane);

        int lg = lgOf(g);
        const float* bptr;
        switch (lg) {
            case 0:  bptr = rIb + ((size_t)(b * 2 + 0) * 2 + 0) * FD; break;
            case 1:  bptr = rIb + ((size_t)(b * 2 + 0) * 2 + 1) * FD; break;
            case 2:  bptr = rIb + ((size_t)(b * 2 + 1) * 2 + 0) * FD; break;
            case 3:  bptr = rIb + ((size_t)(b * 2 + 1) * 2 + 1) * FD; break;
            case 4:  bptr = bd + (size_t)b * FD; break;
            case 5:  bptr = rAb + ((size_t)(b * 2 + 0) * 2 + 0) * FD; break;
            case 6:  bptr = rAb + ((size_t)(b * 2 + 0) * 2 + 1) * FD; break;
            case 7:  bptr = rAb + ((size_t)(b * 2 + 1) * 2 + 0) * FD; break;
            case 8:  bptr = rAb + ((size_t)(b * 2 + 1) * 2 + 1) * FD; break;
            case 9:  bptr = bi + (size_t)(b + 1) * FD; break;
            case 10: bptr = bj + (size_t)(b + 1) * FD; break;
            case 11: bptr = rOb + (size_t)(b * 2 + 0) * FD; break;
            default: bptr = rOb + (size_t)(b * 2 + 1) * FD; break;
        }
        float bv0 = bptr[col0];
        float uv0 = 0.f;
        if (lg == 4) uv0 = u[(size_t)b * FD + col0];

        gemm_core1(Ahi, Alo, Wcur, lane, w, acc1);

        asm volatile("s_waitcnt lgkmcnt(0)\n\ts_barrier" ::: "memory");

        const bool isT = (lg == 0) | (lg == 2) | (lg == 5) | (lg == 7) | (lg == 11);
        const bool isV = (lg == 1) | (lg == 3) | (lg == 6) | (lg == 8) | (lg == 12);
        if (isT) {
#pragma unroll
            for (int reg = 0; reg < 4; ++reg)
                plane_store(Ahi, Alo, hh * 4 + reg, col0, sspf(acc1[reg] + bv0));
        } else if (isV) {
#pragma unroll
            for (int reg = 0; reg < 4; ++reg) {
                int rw = hh * 4 + reg;
                float nv0 = acc1[reg] + bv0 + vreg[reg];
                vreg[reg] = nv0;
                if (lg != 12) plane_store(Ahi, Alo, rw, col0, sspf(nv0));
                if (lg == 8)  X[(size_t)(row0 + rw) * FD + col0] = nv0;
            }
        } else if (lg == 4) {
#pragma unroll
            for (int reg = 0; reg < 4; ++reg) {
                float nv0 = acc1[reg] + bv0 + uv0 * xreg[reg];
                vreg[reg] = nv0;
                plane_store(Ahi, Alo, hh * 4 + reg, col0, sspf(nv0));
            }
        } else if (lg == 9) {
#pragma unroll
            for (int reg = 0; reg < 4; ++reg)
                MI[(size_t)(row0 + hh * 4 + reg) * FD + col0] = sspf(acc1[reg] + bv0);
        } else {   // lg == 10: mj for next block -> fragment layout
#pragma unroll
            for (int reg = 0; reg < 4; ++reg)
                mj_store(mjTg, row0 + hh * 4 + reg, col0, sspf(acc1[reg] + bv0));
        }
    }

    // output projection: e/q = ssp(o) @ Wout + bout
    float pe[4], pq[4];
#pragma unroll
    for (int reg = 0; reg < 4; ++reg) {
        float s0 = sspf(vreg[reg]);
        pe[reg] = s0 * Wout[col0 * 2 + 0];
        pq[reg] = s0 * Wout[col0 * 2 + 1];
#pragma unroll
        for (int mk = 1; mk < 16; mk <<= 1) {
            pe[reg] += __shfl_xor(pe[reg], mk);
            pq[reg] += __shfl_xor(pq[reg], mk);
        }
        if ((lane & 15) == 0) {
            eq[hh * 4 + reg][w][0] = pe[reg];
            eq[hh * 4 + reg][w][1] = pq[reg];
        }
    }
    __syncthreads();
    if (tid < 16) {
        float e = 0.f, q = 0.f;
#pragma unroll
        for (int ww = 0; ww < 8; ++ww) { e += eq[tid][ww][0]; q += eq[tid][ww][1]; }
        Ea[row0 + tid] += e + bout[0];
        Qa[row0 + tid] += q + bout[1];
    }
}

// ---------------- finale (unchanged) ----------------
__global__ __launch_bounds__(256) void k_final(
    const int* __restrict__ Za, const float* __restrict__ Ra,
    const float* __restrict__ Escale, const float* __restrict__ Eshift,
    const float* __restrict__ Qscale, const float* __restrict__ Qshift,
    const float* __restrict__ Ea, const float* __restrict__ Qa,
    float* __restrict__ out)
{
    __shared__ float qs[NPER], es[NPER], px[NPER], py[NPER], pz[NPER];
    __shared__ float red[256];
    const int mol = blockIdx.x, t = threadIdx.x;
    float q = 0.f;
    if (t < NPER) {
        int a = mol * NPER + t;
        int z = Za[a];
        es[t] = Escale[z] * Ea[a] + Eshift[z];
        q = Qscale[z] * Qa[a] + Qshift[z];
        px[t] = Ra[(size_t)a * 3 + 0];
        py[t] = Ra[(size_t)a * 3 + 1];
        pz[t] = Ra[(size_t)a * 3 + 2];
    }
    red[t] = q;
    __syncthreads();
    for (int s = 128; s > 0; s >>= 1) {
        if (t < s) red[t] += red[t + s];
        __syncthreads();
    }
    float qavg = red[0] / (float)NPER;
    __syncthreads();
    if (t < NPER) qs[t] = q - qavg;
    red[t] = 0.f;
    __syncthreads();

    float local = 0.f;
    const float c = SR_CUT_C * 0.5f;
    for (int p = t; p < NPER * NPER; p += 256) {
        int i = p / NPER, j = p % NPER;
        if (i == j) continue;
        float dx = px[i] - px[j], dy = py[i] - py[j], dz = pz[i] - pz[j];
        float d2 = dx * dx + dy * dy + dz * dz;
        float d = sqrtf(d2);
        float dS = sqrtf(d2 + 1.0f);
        float sw;
        if (d < c) {
            float xs = d / c;
            float xs2 = xs * xs, xs3 = xs2 * xs;
            sw = xs3 * (6.0f * xs2 - 15.0f * xs + 10.0f);
        } else {
            sw = 1.0f;
        }
        local += KEHALF_C * qs[i] * qs[j] * ((1.0f - sw) / dS + sw / d);
    }
    for (int a = t; a < NPER; a += 256) local += es[a];
    red[t] = local;
    __syncthreads();
    for (int s = 128; s > 0; s >>= 1) {
        if (t < s) red[t] += red[t + s];
        __syncthreads();
    }
    if (t == 0) out[mol] = red[0];
}

extern "C" void kernel_launch(void* const* d_in, const int* in_sizes, int n_in,
                              void* d_out, int out_size, void* d_ws, size_t ws_size,
                              hipStream_t stream)
{
    (void)in_sizes; (void)n_in; (void)out_size; (void)ws_size;

    const int*   Za     = (const int*)d_in[0];
    const float* Ra     = (const float*)d_in[1];
    const float* emb    = (const float*)d_in[5];
    const float* rbfc   = (const float*)d_in[6];
    const float* rbfw   = (const float*)d_in[7];
    const float* Wrbf   = (const float*)d_in[8];
    const float* Wi     = (const float*)d_in[9];
    const float* bi     = (const float*)d_in[10];
    const float* Wj     = (const float*)d_in[11];
    const float* bj     = (const float*)d_in[12];
    const float* rIW    = (const float*)d_in[13];
    const float* rIb    = (const float*)d_in[14];
    const float* Wd     = (const float*)d_in[15];
    const float* bd     = (const float*)d_in[16];
    const float* u      = (const float*)d_in[17];
    const float* rAW    = (const float*)d_in[18];
    const float* rAb    = (const float*)d_in[19];
    const float* rOW    = (const float*)d_in[20];
    const float* rOb    = (const float*)d_in[21];
    const float* Wout   = (const float*)d_in[22];
    const float* bout   = (const float*)d_in[23];
    const float* Escale = (const float*)d_in[24];
    const float* Eshift = (const float*)d_in[25];
    const float* Qscale = (const float*)d_in[26];
    const float* Qshift = (const float*)d_in[27];
    float* outp = (float*)d_out;

    float* ws = (float*)d_ws;
    const size_t NF = (size_t)NATOM * FD;
    float* x  = ws;
    float* mi = ws + NF;
    float* Ea = ws + 2 * NF;
    float* Qa = Ea + NATOM;
    short* prepW = (short*)(ws + 2 * NF + 2 * NATOM);
    short* mjTg  = prepW + (size_t)67 * 32768;

    k_prep<<<67, 256, 0, stream>>>(Wi, Wj, rIW, Wd, rAW, rOW, prepW);
    k_first<<<NATOM / 16, 256, 0, stream>>>(Za, emb, prepW, bi, bj, x, mi, mjTg, Ea, Qa);

    for (int b = 0; b < NBLOCK; ++b) {
        k_fused<<<NATOM / 16, 512, 0, stream>>>(
            Ra, x, prepW, b, rbfc, rbfw, Wrbf + (size_t)b * KR * FD,
            rIb, bd, u, rAb, bi, bj, rOb,
            Wout + (size_t)b * FD * 2, bout + b * 2, mi, mjTg, Ea, Qa);
    }

    k_final<<<NMOL, 256, 0, stream>>>(Za, Ra, Escale, Eshift, Qscale, Qshift, Ea, Qa, outp);
}